// Round 2
// baseline (14001.364 us; speedup 1.0000x reference)
//
#include <hip/hip_runtime.h>
#include <math.h>

#define NTOK 16000
#define E    512
#define FFD  2048
#define CBN  4096
#define SEQ  1000
#define NH   8

__device__ __forceinline__ float gelu_f(float v) {
    return 0.5f * v * (1.0f + erff(v * 0.70710678118654752f));
}

// ---------------------------------------------------------------- embed
__global__ __launch_bounds__(128) void embed_kernel(const int* __restrict__ tok,
                                                    const float* __restrict__ cb,
                                                    const float* __restrict__ pe,
                                                    float* __restrict__ x,
                                                    float* __restrict__ y) {
    const int row = blockIdx.x;
    const int s = row % SEQ;
    const int t = tok[row];
    const int c = threadIdx.x * 4;
    const float4 cv = *(const float4*)(cb + (size_t)t * E + c);
    const float4 pv = *(const float4*)(pe + (size_t)s * E + c);
    float4 v;
    v.x = cv.x + pv.x; v.y = cv.y + pv.y; v.z = cv.z + pv.z; v.w = cv.w + pv.w;
    *(float4*)(x + (size_t)row * E + c) = v;
    *(float4*)(y + (size_t)row * E + c) = v;
}

// ---------------------------------------------------------------- layernorm (1 wave / row)
template<int GELU>
__global__ __launch_bounds__(256) void ln_kernel(const float* __restrict__ in,
                                                 float* __restrict__ out,
                                                 const float* __restrict__ g,
                                                 const float* __restrict__ b) {
    const int lane = threadIdx.x & 63;
    const int row = blockIdx.x * 4 + (threadIdx.x >> 6);
    const float* p = in + (size_t)row * E;
    const float4 v0 = *(const float4*)(p + lane * 4);
    const float4 v1 = *(const float4*)(p + 256 + lane * 4);
    float sum = v0.x + v0.y + v0.z + v0.w + v1.x + v1.y + v1.z + v1.w;
    float sq = v0.x * v0.x + v0.y * v0.y + v0.z * v0.z + v0.w * v0.w
             + v1.x * v1.x + v1.y * v1.y + v1.z * v1.z + v1.w * v1.w;
#pragma unroll
    for (int m = 1; m < 64; m <<= 1) {
        sum += __shfl_xor(sum, m);
        sq += __shfl_xor(sq, m);
    }
    const float mean = sum * (1.0f / 512.0f);
    const float var = sq * (1.0f / 512.0f) - mean * mean;
    const float rstd = rsqrtf(var + 1e-5f);
    const float4 g0 = *(const float4*)(g + lane * 4);
    const float4 g1 = *(const float4*)(g + 256 + lane * 4);
    const float4 b0 = *(const float4*)(b + lane * 4);
    const float4 b1 = *(const float4*)(b + 256 + lane * 4);
    float4 o0, o1;
    o0.x = (v0.x - mean) * rstd * g0.x + b0.x;
    o0.y = (v0.y - mean) * rstd * g0.y + b0.y;
    o0.z = (v0.z - mean) * rstd * g0.z + b0.z;
    o0.w = (v0.w - mean) * rstd * g0.w + b0.w;
    o1.x = (v1.x - mean) * rstd * g1.x + b1.x;
    o1.y = (v1.y - mean) * rstd * g1.y + b1.y;
    o1.z = (v1.z - mean) * rstd * g1.z + b1.z;
    o1.w = (v1.w - mean) * rstd * g1.w + b1.w;
    if (GELU) {
        o0.x = gelu_f(o0.x); o0.y = gelu_f(o0.y); o0.z = gelu_f(o0.z); o0.w = gelu_f(o0.w);
        o1.x = gelu_f(o1.x); o1.y = gelu_f(o1.y); o1.z = gelu_f(o1.z); o1.w = gelu_f(o1.w);
    }
    float* q = out + (size_t)row * E;
    *(float4*)(q + lane * 4) = o0;
    *(float4*)(q + 256 + lane * 4) = o1;
}

// ---------------------------------------------------------------- GEMM  C[r,c] = A[r,:].W[c,:] + bias (+gelu)(+R + s*)
// tile: 128 rows x 64 cols, K-chunk 16, 256 threads, per-thread 8x4
// bias == nullptr -> treated as zero
template<int GELU, int RES>
__global__ __launch_bounds__(256) void gemm_nt(const float* __restrict__ A, int lda,
                                               const float* __restrict__ W, int ldw,
                                               const float* __restrict__ bias,
                                               const float* __restrict__ Rres,
                                               const float* __restrict__ scale_ptr,
                                               float* __restrict__ C, int ldc, int K) {
    __shared__ float As[16][136];
    __shared__ float Ws[16][72];
    const int tid = threadIdx.x;
    const int tx = tid & 15, ty = tid >> 4;
    const int rowBase = blockIdx.y * 128;
    const int colBase = blockIdx.x * 64;
    const int lr = tid >> 2;
    const int lk = (tid & 3) << 2;
    const float* Ap0 = A + (size_t)(rowBase + lr) * lda + lk;
    const float* Ap1 = A + (size_t)(rowBase + lr + 64) * lda + lk;
    const float* Wp = W + (size_t)(colBase + lr) * ldw + lk;
    float acc[8][4] = {};
    for (int k0 = 0; k0 < K; k0 += 16) {
        const float4 a0 = *(const float4*)(Ap0 + k0);
        const float4 a1 = *(const float4*)(Ap1 + k0);
        const float4 w0 = *(const float4*)(Wp + k0);
        __syncthreads();
        As[lk + 0][lr] = a0.x; As[lk + 1][lr] = a0.y; As[lk + 2][lr] = a0.z; As[lk + 3][lr] = a0.w;
        As[lk + 0][lr + 64] = a1.x; As[lk + 1][lr + 64] = a1.y; As[lk + 2][lr + 64] = a1.z; As[lk + 3][lr + 64] = a1.w;
        Ws[lk + 0][lr] = w0.x; Ws[lk + 1][lr] = w0.y; Ws[lk + 2][lr] = w0.z; Ws[lk + 3][lr] = w0.w;
        __syncthreads();
#pragma unroll
        for (int kk = 0; kk < 16; ++kk) {
            const float4 alo = *(const float4*)&As[kk][ty * 8];
            const float4 ahi = *(const float4*)&As[kk][ty * 8 + 4];
            const float4 bb = *(const float4*)&Ws[kk][tx * 4];
            const float av[8] = {alo.x, alo.y, alo.z, alo.w, ahi.x, ahi.y, ahi.z, ahi.w};
            const float bv[4] = {bb.x, bb.y, bb.z, bb.w};
#pragma unroll
            for (int i = 0; i < 8; ++i)
#pragma unroll
                for (int j = 0; j < 4; ++j)
                    acc[i][j] += av[i] * bv[j];
        }
    }
    float sc = 1.0f;
    if (RES && scale_ptr) sc = *scale_ptr;
    float bvv[4] = {0.f, 0.f, 0.f, 0.f};
    if (bias) {
        const float4 bb = *(const float4*)(bias + colBase + tx * 4);
        bvv[0] = bb.x; bvv[1] = bb.y; bvv[2] = bb.z; bvv[3] = bb.w;
    }
#pragma unroll
    for (int i = 0; i < 8; ++i) {
        const int r = rowBase + ty * 8 + i;
        float vv[4];
#pragma unroll
        for (int j = 0; j < 4; ++j) {
            float v = acc[i][j] + bvv[j];
            if (GELU) v = gelu_f(v);
            vv[j] = v;
        }
        float* cp = C + (size_t)r * ldc + colBase + tx * 4;
        if (RES) {
            const float4 rr = *(const float4*)(Rres + (size_t)r * ldc + colBase + tx * 4);
            vv[0] = rr.x + sc * vv[0]; vv[1] = rr.y + sc * vv[1];
            vv[2] = rr.z + sc * vv[2]; vv[3] = rr.w + sc * vv[3];
        }
        *(float4*)cp = make_float4(vv[0], vv[1], vv[2], vv[3]);
    }
}

// ---------------------------------------------------------------- flash attention, q-tile 64 x k-tile 64
__global__ __launch_bounds__(256) void attn_kernel(const float* __restrict__ qkv,
                                                   float* __restrict__ ctx) {
    __shared__ float Qs[64][68];
    __shared__ float Ks[64][68];   // reused to hold P after scores
    __shared__ float Vs[64][68];
    const int tid = threadIdx.x;
    const int tx = tid & 15, ty = tid >> 4;
    const int qt = blockIdx.x;       // 16 q tiles
    const int bh = blockIdx.y;       // 128 = b*8+h
    const int b = bh >> 3, h = bh & 7;
    const int lrow = tid >> 4;       // 0..15
    const int lcol = (tid & 15) * 4; // 0..60
#pragma unroll
    for (int p = 0; p < 4; ++p) {
        const int rr = p * 16 + lrow;
        const int q = qt * 64 + rr;
        float4 v = make_float4(0.f, 0.f, 0.f, 0.f);
        if (q < SEQ) v = *(const float4*)(qkv + (size_t)(b * SEQ + q) * 1536 + h * 64 + lcol);
        *(float4*)&Qs[rr][lcol] = v;
    }
    float m_i[4] = {-3e38f, -3e38f, -3e38f, -3e38f};
    float l_i[4] = {0.f, 0.f, 0.f, 0.f};
    float o[4][4] = {};
    for (int kb = 0; kb < SEQ; kb += 64) {
        __syncthreads();
#pragma unroll
        for (int p = 0; p < 4; ++p) {
            const int rr = p * 16 + lrow;
            const int kr = kb + rr;
            float4 kv = make_float4(0.f, 0.f, 0.f, 0.f);
            float4 vv = make_float4(0.f, 0.f, 0.f, 0.f);
            if (kr < SEQ) {
                const float* base = qkv + (size_t)(b * SEQ + kr) * 1536 + h * 64 + lcol;
                kv = *(const float4*)(base + 512);
                vv = *(const float4*)(base + 1024);
            }
            *(float4*)&Ks[rr][lcol] = kv;
            *(float4*)&Vs[rr][lcol] = vv;
        }
        __syncthreads();
        float s[4][4] = {};
#pragma unroll
        for (int d0 = 0; d0 < 64; d0 += 4) {
            float4 qv[4], kv[4];
#pragma unroll
            for (int i = 0; i < 4; ++i) qv[i] = *(const float4*)&Qs[ty * 4 + i][d0];
#pragma unroll
            for (int j = 0; j < 4; ++j) kv[j] = *(const float4*)&Ks[tx * 4 + j][d0];
#pragma unroll
            for (int i = 0; i < 4; ++i)
#pragma unroll
                for (int j = 0; j < 4; ++j)
                    s[i][j] += qv[i].x * kv[j].x + qv[i].y * kv[j].y
                             + qv[i].z * kv[j].z + qv[i].w * kv[j].w;
        }
#pragma unroll
        for (int i = 0; i < 4; ++i) {
            float rm = -3e38f;
#pragma unroll
            for (int j = 0; j < 4; ++j) {
                const int kc = kb + tx * 4 + j;
                s[i][j] = (kc < SEQ) ? s[i][j] * 0.125f : -3e38f;
                rm = fmaxf(rm, s[i][j]);
            }
#pragma unroll
            for (int m = 1; m < 16; m <<= 1) rm = fmaxf(rm, __shfl_xor(rm, m));
            const float mn = fmaxf(m_i[i], rm);
            const float alpha = expf(m_i[i] - mn);
            float rs = 0.f;
#pragma unroll
            for (int j = 0; j < 4; ++j) {
                const float pv = expf(s[i][j] - mn);
                s[i][j] = pv;
                rs += pv;
            }
#pragma unroll
            for (int m = 1; m < 16; m <<= 1) rs += __shfl_xor(rs, m);
            l_i[i] = l_i[i] * alpha + rs;
            m_i[i] = mn;
            o[i][0] *= alpha; o[i][1] *= alpha; o[i][2] *= alpha; o[i][3] *= alpha;
        }
        __syncthreads();
#pragma unroll
        for (int i = 0; i < 4; ++i)
            *(float4*)&Ks[ty * 4 + i][tx * 4] = make_float4(s[i][0], s[i][1], s[i][2], s[i][3]);
        __syncthreads();
#pragma unroll
        for (int k4 = 0; k4 < 64; k4 += 4) {
            float4 pv[4], vv[4];
#pragma unroll
            for (int i = 0; i < 4; ++i) pv[i] = *(const float4*)&Ks[ty * 4 + i][k4];
#pragma unroll
            for (int t = 0; t < 4; ++t) vv[t] = *(const float4*)&Vs[k4 + t][tx * 4];
#pragma unroll
            for (int i = 0; i < 4; ++i) {
                o[i][0] += pv[i].x * vv[0].x + pv[i].y * vv[1].x + pv[i].z * vv[2].x + pv[i].w * vv[3].x;
                o[i][1] += pv[i].x * vv[0].y + pv[i].y * vv[1].y + pv[i].z * vv[2].y + pv[i].w * vv[3].y;
                o[i][2] += pv[i].x * vv[0].z + pv[i].y * vv[1].z + pv[i].z * vv[2].z + pv[i].w * vv[3].z;
                o[i][3] += pv[i].x * vv[0].w + pv[i].y * vv[1].w + pv[i].z * vv[2].w + pv[i].w * vv[3].w;
            }
        }
    }
#pragma unroll
    for (int i = 0; i < 4; ++i) {
        const int q = qt * 64 + ty * 4 + i;
        if (q < SEQ) {
            const float inv = 1.0f / l_i[i];
            *(float4*)(ctx + (size_t)(b * SEQ + q) * E + h * 64 + tx * 4) =
                make_float4(o[i][0] * inv, o[i][1] * inv, o[i][2] * inv, o[i][3] * inv);
        }
    }
}

// ---------------------------------------------------------------- codebook row norms
__global__ __launch_bounds__(256) void cbnorm_kernel(const float* __restrict__ cb,
                                                     float* __restrict__ out) {
    const int lane = threadIdx.x & 63;
    const int row = blockIdx.x * 4 + (threadIdx.x >> 6);
    const float* p = cb + (size_t)row * E;
    const float4 v0 = *(const float4*)(p + lane * 4);
    const float4 v1 = *(const float4*)(p + 256 + lane * 4);
    float sq = v0.x * v0.x + v0.y * v0.y + v0.z * v0.z + v0.w * v0.w
             + v1.x * v1.x + v1.y * v1.y + v1.z * v1.z + v1.w * v1.w;
#pragma unroll
    for (int m = 1; m < 64; m <<= 1) sq += __shfl_xor(sq, m);
    if (lane == 0) out[row] = sq;
}

// ---------------------------------------------------------------- fused distance+argmin over a 1024-entry codebook chunk
__global__ __launch_bounds__(256) void argmin_kernel(const float* __restrict__ fc,
                                                     const float* __restrict__ cb,
                                                     const float* __restrict__ cbn,
                                                     float* __restrict__ pbv,
                                                     float* __restrict__ pbi) {
    __shared__ float As[16][72];
    __shared__ float Ws[16][72];
    const int tid = threadIdx.x;
    const int tx = tid & 15, ty = tid >> 4;
    const int rowBase = blockIdx.y * 64;
    const int chunk = blockIdx.x;
    const int lr = tid >> 2;
    const int lk = (tid & 3) << 2;
    float bestv[4] = {3e38f, 3e38f, 3e38f, 3e38f};
    int besti[4] = {0, 0, 0, 0};
    const float* Ap = fc + (size_t)(rowBase + lr) * E + lk;
    for (int ct = 0; ct < 16; ++ct) {
        const int colBase = chunk * 1024 + ct * 64;
        const float* Wp = cb + (size_t)(colBase + lr) * E + lk;
        float acc[4][4] = {};
        for (int k0 = 0; k0 < E; k0 += 16) {
            const float4 a = *(const float4*)(Ap + k0);
            const float4 w = *(const float4*)(Wp + k0);
            __syncthreads();
            As[lk + 0][lr] = a.x; As[lk + 1][lr] = a.y; As[lk + 2][lr] = a.z; As[lk + 3][lr] = a.w;
            Ws[lk + 0][lr] = w.x; Ws[lk + 1][lr] = w.y; Ws[lk + 2][lr] = w.z; Ws[lk + 3][lr] = w.w;
            __syncthreads();
#pragma unroll
            for (int kk = 0; kk < 16; ++kk) {
                const float4 a4 = *(const float4*)&As[kk][ty * 4];
                const float4 b4 = *(const float4*)&Ws[kk][tx * 4];
                const float av[4] = {a4.x, a4.y, a4.z, a4.w};
                const float bv[4] = {b4.x, b4.y, b4.z, b4.w};
#pragma unroll
                for (int i = 0; i < 4; ++i)
#pragma unroll
                    for (int j = 0; j < 4; ++j)
                        acc[i][j] += av[i] * bv[j];
            }
        }
        const float4 n4 = *(const float4*)(cbn + colBase + tx * 4);
        const float nv[4] = {n4.x, n4.y, n4.z, n4.w};
#pragma unroll
        for (int i = 0; i < 4; ++i)
#pragma unroll
            for (int j = 0; j < 4; ++j) {
                const float d = nv[j] - 2.0f * acc[i][j];
                const int idx = colBase + tx * 4 + j;
                if (d < bestv[i]) { bestv[i] = d; besti[i] = idx; }
            }
    }
#pragma unroll
    for (int i = 0; i < 4; ++i) {
        float bv = bestv[i];
        int bi = besti[i];
#pragma unroll
        for (int m = 1; m < 16; m <<= 1) {
            const float ov = __shfl_xor(bv, m);
            const int oi = __shfl_xor(bi, m);
            if (ov < bv || (ov == bv && oi < bi)) { bv = ov; bi = oi; }
        }
        if (tx == 0) {
            const int r = rowBase + ty * 4 + i;
            pbv[(size_t)r * 4 + chunk] = bv;
            pbi[(size_t)r * 4 + chunk] = (float)bi;
        }
    }
}

__global__ __launch_bounds__(256) void argmin_combine(const float* __restrict__ pbv,
                                                      const float* __restrict__ pbi,
                                                      float* __restrict__ tokf) {
    const int r = blockIdx.x * 256 + threadIdx.x;
    if (r >= NTOK) return;
    float bv = pbv[(size_t)r * 4];
    float bi = pbi[(size_t)r * 4];
#pragma unroll
    for (int c = 1; c < 4; ++c) {
        const float v = pbv[(size_t)r * 4 + c];
        if (v < bv) { bv = v; bi = pbi[(size_t)r * 4 + c]; }
    }
    tokf[r] = bi;
}

// ---------------------------------------------------------------- launch
extern "C" void kernel_launch(void* const* d_in, const int* in_sizes, int n_in,
                              void* d_out, int out_size, void* d_ws, size_t ws_size,
                              hipStream_t stream) {
    const int* noisy = (const int*)d_in[0];
    const float* codebook = (const float*)d_in[1];
    const float* pos_enc = (const float*)d_in[2];
    const float* qkv_w = (const float*)d_in[3];
    const float* qkv_b = (const float*)d_in[4];
    const float* out_w = (const float*)d_in[5];
    const float* out_b = (const float*)d_in[6];
    const float* ln1_g = (const float*)d_in[7];
    const float* ln1_b = (const float*)d_in[8];
    const float* ln2_g = (const float*)d_in[9];
    const float* ln2_b = (const float*)d_in[10];
    const float* ff1_w = (const float*)d_in[11];
    const float* ff1_b = (const float*)d_in[12];
    const float* ff2_w = (const float*)d_in[13];
    const float* ff2_b = (const float*)d_in[14];
    const float* fin_g = (const float*)d_in[15];
    const float* fin_b = (const float*)d_in[16];
    const float* pp1_w = (const float*)d_in[17];
    const float* pp1_b = (const float*)d_in[18];
    const float* pp_ln_g = (const float*)d_in[19];
    const float* pp_ln_b = (const float*)d_in[20];
    const float* pp2_w = (const float*)d_in[21];
    const float* pp2_b = (const float*)d_in[22];
    const float* res_w = (const float*)d_in[23];
    const float* fc1_w = (const float*)d_in[24];
    const float* fc1_b = (const float*)d_in[25];
    const float* fc_ln_g = (const float*)d_in[26];
    const float* fc_ln_b = (const float*)d_in[27];
    const float* fc2_w = (const float*)d_in[28];
    const float* fc2_b = (const float*)d_in[29];

    // workspace layout (floats): total 41,092,096 ≈ 164 MB
    float* ws = (float*)d_ws;
    float* y = ws;                        // 8,192,000
    float* h = ws + 8192000;              // 8,192,000
    float* big = ws + 16384000;           // 24,576,000 (qkv; FF mid reuses first 8.192M)
    float* cbn = ws + 40960000;           // 4,096
    float* pbv = ws + 40964096;           // 64,000
    float* pbi = ws + 41028096;           // 64,000
    // x (embed output, used only for the final residual) lives in d_out;
    // it is dead before fc overwrites d_out at the end.
    float* x = (float*)d_out;

    embed_kernel<<<dim3(NTOK), dim3(128), 0, stream>>>(noisy, codebook, pos_enc, x, y);
    cbnorm_kernel<<<dim3(1024), dim3(256), 0, stream>>>(codebook, cbn);

    for (int l = 0; l < 4; ++l) {
        ln_kernel<0><<<dim3(4000), dim3(256), 0, stream>>>(y, h, ln1_g + l * E, ln1_b + l * E);
        gemm_nt<0, 0><<<dim3(24, 125), dim3(256), 0, stream>>>(
            h, E, qkv_w + (size_t)l * 1536 * E, E, qkv_b + (size_t)l * 1536,
            nullptr, nullptr, big, 1536, E);
        attn_kernel<<<dim3(16, 128), dim3(256), 0, stream>>>(big, h);
        gemm_nt<0, 1><<<dim3(8, 125), dim3(256), 0, stream>>>(
            h, E, out_w + (size_t)l * E * E, E, out_b + (size_t)l * E,
            y, nullptr, y, E, E);
        ln_kernel<0><<<dim3(4000), dim3(256), 0, stream>>>(y, h, ln2_g + l * E, ln2_b + l * E);
        // FF split into 4 column chunks of 512; mid reuses qkv region
        float* mid = big;
        for (int c = 0; c < 4; ++c) {
            gemm_nt<1, 0><<<dim3(8, 125), dim3(256), 0, stream>>>(
                h, E, ff1_w + ((size_t)l * FFD + c * 512) * E, E,
                ff1_b + (size_t)l * FFD + c * 512,
                nullptr, nullptr, mid, 512, E);
            gemm_nt<0, 1><<<dim3(8, 125), dim3(256), 0, stream>>>(
                mid, 512, ff2_w + (size_t)l * E * FFD + c * 512, FFD,
                (c == 0) ? (ff2_b + (size_t)l * E) : nullptr,
                y, nullptr, y, E, 512);
        }
    }

    ln_kernel<0><<<dim3(4000), dim3(256), 0, stream>>>(y, h, fin_g, fin_b);
    gemm_nt<0, 0><<<dim3(8, 125), dim3(256), 0, stream>>>(
        h, E, pp1_w, E, pp1_b, nullptr, nullptr, big, E, E);
    ln_kernel<1><<<dim3(4000), dim3(256), 0, stream>>>(big, h, pp_ln_g, pp_ln_b);
    // enhanced = x + res_w * (h @ pp2^T + b)  -> y   (x == d_out, read-only here)
    gemm_nt<0, 1><<<dim3(8, 125), dim3(256), 0, stream>>>(
        h, E, pp2_w, E, pp2_b, x, res_w, y, E, E);
    gemm_nt<0, 0><<<dim3(8, 125), dim3(256), 0, stream>>>(
        y, E, fc1_w, E, fc1_b, nullptr, nullptr, big, E, E);
    ln_kernel<1><<<dim3(4000), dim3(256), 0, stream>>>(big, h, fc_ln_g, fc_ln_b);

    float* fco = (float*)d_out;   // overwrites x, which is dead now
    gemm_nt<0, 0><<<dim3(8, 125), dim3(256), 0, stream>>>(
        h, E, fc2_w, E, fc2_b, nullptr, nullptr, fco, E, E);

    argmin_kernel<<<dim3(4, 250), dim3(256), 0, stream>>>(fco, codebook, cbn, pbv, pbi);
    argmin_combine<<<dim3(63), dim3(256), 0, stream>>>(pbv, pbi, fco + 8192000);
}

// Round 3
// 9819.965 us; speedup vs baseline: 1.4258x; 1.4258x over previous
//
#include <hip/hip_runtime.h>
#include <hip/hip_bf16.h>
#include <math.h>

#define NTOK 16000
#define E    512
#define FFD  2048
#define CBN  4096
#define SEQ  1000
#define NH   8

typedef __hip_bfloat16 bf16;
typedef __attribute__((ext_vector_type(8))) short short8;
typedef __attribute__((ext_vector_type(4))) float f32x4;

__device__ __forceinline__ float gelu_f(float v) {
    return 0.5f * v * (1.0f + erff(v * 0.70710678118654752f));
}

__device__ __forceinline__ void split_store(float v, bf16* hi, bf16* lo, size_t idx) {
    bf16 h = __float2bfloat16(v);
    hi[idx] = h;
    lo[idx] = __float2bfloat16(v - __bfloat162float(h));
}

// ---------------------------------------------------------------- embed -> y (fp32)
__global__ __launch_bounds__(128) void embed_kernel(const int* __restrict__ tok,
                                                    const float* __restrict__ cb,
                                                    const float* __restrict__ pe,
                                                    float* __restrict__ y) {
    const int row = blockIdx.x;
    const int s = row % SEQ;
    const int t = tok[row];
    const int c = threadIdx.x * 4;
    const float4 cv = *(const float4*)(cb + (size_t)t * E + c);
    const float4 pv = *(const float4*)(pe + (size_t)s * E + c);
    *(float4*)(y + (size_t)row * E + c) =
        make_float4(cv.x + pv.x, cv.y + pv.y, cv.z + pv.z, cv.w + pv.w);
}

// ---------------------------------------------------------------- weight split fp32 -> hi/lo bf16 (compact dst)
__global__ __launch_bounds__(256) void split_w(const float* __restrict__ src, int ld,
                                               int cols_log2, int n,
                                               bf16* __restrict__ hi, bf16* __restrict__ lo) {
    const int i = blockIdx.x * 256 + threadIdx.x;
    if (i >= n) return;
    const int r = i >> cols_log2;
    const int c = i & ((1 << cols_log2) - 1);
    const float v = src[(size_t)r * ld + c];
    split_store(v, hi, lo, i);
}

// ---------------------------------------------------------------- layernorm -> hi/lo planes (1 wave/row)
template<int GELU>
__global__ __launch_bounds__(256) void ln_planes(const float* __restrict__ in,
                                                 bf16* __restrict__ hi, bf16* __restrict__ lo,
                                                 const float* __restrict__ g,
                                                 const float* __restrict__ b) {
    const int lane = threadIdx.x & 63;
    const int row = blockIdx.x * 4 + (threadIdx.x >> 6);
    const float* p = in + (size_t)row * E;
    const float4 v0 = *(const float4*)(p + lane * 4);
    const float4 v1 = *(const float4*)(p + 256 + lane * 4);
    float sum = v0.x + v0.y + v0.z + v0.w + v1.x + v1.y + v1.z + v1.w;
    float sq = v0.x * v0.x + v0.y * v0.y + v0.z * v0.z + v0.w * v0.w
             + v1.x * v1.x + v1.y * v1.y + v1.z * v1.z + v1.w * v1.w;
#pragma unroll
    for (int m = 1; m < 64; m <<= 1) {
        sum += __shfl_xor(sum, m);
        sq += __shfl_xor(sq, m);
    }
    const float mean = sum * (1.0f / 512.0f);
    const float var = sq * (1.0f / 512.0f) - mean * mean;
    const float rstd = rsqrtf(var + 1e-5f);
    const float4 g0 = *(const float4*)(g + lane * 4);
    const float4 g1 = *(const float4*)(g + 256 + lane * 4);
    const float4 b0 = *(const float4*)(b + lane * 4);
    const float4 b1 = *(const float4*)(b + 256 + lane * 4);
    const size_t base = (size_t)row * E;
    float o;
    const float vv0[4] = {v0.x, v0.y, v0.z, v0.w};
    const float gg0[4] = {g0.x, g0.y, g0.z, g0.w};
    const float bb0[4] = {b0.x, b0.y, b0.z, b0.w};
    const float vv1[4] = {v1.x, v1.y, v1.z, v1.w};
    const float gg1[4] = {g1.x, g1.y, g1.z, g1.w};
    const float bb1[4] = {b1.x, b1.y, b1.z, b1.w};
#pragma unroll
    for (int t = 0; t < 4; ++t) {
        o = (vv0[t] - mean) * rstd * gg0[t] + bb0[t];
        if (GELU) o = gelu_f(o);
        split_store(o, hi, lo, base + lane * 4 + t);
        o = (vv1[t] - mean) * rstd * gg1[t] + bb1[t];
        if (GELU) o = gelu_f(o);
        split_store(o, hi, lo, base + 256 + lane * 4 + t);
    }
}

// ---------------------------------------------------------------- split-bf16 MFMA NT GEMM
// C[M,N] = A[M,:]·W[N,:]^T via (Ah+Al)(Wh+Wl) ≈ AhWh + AhWl + AlWh
// 128x128 tile, BK=32, 256 threads = 4 waves (2x2 of 64x64)
// OUT: 0 = C fp32 (+bias); 1 = C += (+bias) (residual RMW); 2 = gelu -> planes;
//      3 = emb(r,c) + resw*(v+bias) -> planes
template<int OUT>
__global__ __launch_bounds__(256) void gemm_split(
    const bf16* __restrict__ Ah, const bf16* __restrict__ Al, int lda,
    const bf16* __restrict__ Wh, const bf16* __restrict__ Wl, int ldw,
    const float* __restrict__ bias,
    float* __restrict__ C, int ldc,
    bf16* __restrict__ Ohi, bf16* __restrict__ Olo, int ldp,
    const int* __restrict__ noisy, const float* __restrict__ cb,
    const float* __restrict__ pe, const float* __restrict__ resw,
    int K) {
    __shared__ short Ash[2][128][40];   // [plane][row][k + 8 pad]
    __shared__ short Wsh[2][128][40];
    const int tid = threadIdx.x;
    const int rowBase = blockIdx.y * 128;
    const int colBase = blockIdx.x * 128;
    const int wave = tid >> 6, lane = tid & 63;
    const int wm = (wave & 1) * 64, wn = (wave >> 1) * 64;
    const int lm = lane & 15;
    const int q8 = (lane >> 4) * 8;
    const int r0 = tid >> 2;          // 0..63
    const int kq = (tid & 3) * 8;     // 0,8,16,24

    f32x4 acc[4][4];
#pragma unroll
    for (int i = 0; i < 4; ++i)
#pragma unroll
        for (int j = 0; j < 4; ++j)
            acc[i][j] = (f32x4){0.f, 0.f, 0.f, 0.f};

    for (int k0 = 0; k0 < K; k0 += 32) {
        __syncthreads();
        {
            const size_t a0 = (size_t)(rowBase + r0) * lda + k0 + kq;
            const size_t a1 = (size_t)(rowBase + r0 + 64) * lda + k0 + kq;
            const size_t w0 = (size_t)(colBase + r0) * ldw + k0 + kq;
            const size_t w1 = (size_t)(colBase + r0 + 64) * ldw + k0 + kq;
            *(short8*)&Ash[0][r0][kq]      = *(const short8*)(Ah + a0);
            *(short8*)&Ash[0][r0 + 64][kq] = *(const short8*)(Ah + a1);
            *(short8*)&Ash[1][r0][kq]      = *(const short8*)(Al + a0);
            *(short8*)&Ash[1][r0 + 64][kq] = *(const short8*)(Al + a1);
            *(short8*)&Wsh[0][r0][kq]      = *(const short8*)(Wh + w0);
            *(short8*)&Wsh[0][r0 + 64][kq] = *(const short8*)(Wh + w1);
            *(short8*)&Wsh[1][r0][kq]      = *(const short8*)(Wl + w0);
            *(short8*)&Wsh[1][r0 + 64][kq] = *(const short8*)(Wl + w1);
        }
        __syncthreads();
        short8 ah[4], al[4], wh[4], wl[4];
#pragma unroll
        for (int i = 0; i < 4; ++i) {
            ah[i] = *(const short8*)&Ash[0][wm + i * 16 + lm][q8];
            al[i] = *(const short8*)&Ash[1][wm + i * 16 + lm][q8];
            wh[i] = *(const short8*)&Wsh[0][wn + i * 16 + lm][q8];
            wl[i] = *(const short8*)&Wsh[1][wn + i * 16 + lm][q8];
        }
#pragma unroll
        for (int i = 0; i < 4; ++i)
#pragma unroll
            for (int j = 0; j < 4; ++j)
                acc[i][j] = __builtin_amdgcn_mfma_f32_16x16x32_bf16(ah[i], wh[j], acc[i][j], 0, 0, 0);
#pragma unroll
        for (int i = 0; i < 4; ++i)
#pragma unroll
            for (int j = 0; j < 4; ++j)
                acc[i][j] = __builtin_amdgcn_mfma_f32_16x16x32_bf16(ah[i], wl[j], acc[i][j], 0, 0, 0);
#pragma unroll
        for (int i = 0; i < 4; ++i)
#pragma unroll
            for (int j = 0; j < 4; ++j)
                acc[i][j] = __builtin_amdgcn_mfma_f32_16x16x32_bf16(al[i], wh[j], acc[i][j], 0, 0, 0);
    }

    // epilogue: C/D layout col = lane&15, row = (lane>>4)*4 + reg [m89-verified]
    float bv[4];
#pragma unroll
    for (int j = 0; j < 4; ++j)
        bv[j] = bias ? bias[colBase + wn + j * 16 + lm] : 0.f;
    float scv = 0.f;
    if (OUT == 3) scv = resw[0];
#pragma unroll
    for (int i = 0; i < 4; ++i) {
#pragma unroll
        for (int reg = 0; reg < 4; ++reg) {
            const int r = rowBase + wm + i * 16 + (lane >> 4) * 4 + reg;
            int tok = 0, srow = 0;
            if (OUT == 3) { tok = noisy[r]; srow = r % SEQ; }
#pragma unroll
            for (int j = 0; j < 4; ++j) {
                const int col = colBase + wn + j * 16 + lm;
                float v = acc[i][j][reg] + bv[j];
                if (OUT == 0) {
                    C[(size_t)r * ldc + col] = v;
                } else if (OUT == 1) {
                    float* cp = C + (size_t)r * ldc + col;
                    *cp = *cp + v;
                } else if (OUT == 2) {
                    v = gelu_f(v);
                    split_store(v, Ohi, Olo, (size_t)r * ldp + col);
                } else { // OUT == 3
                    const float xv = cb[(size_t)tok * E + col] + pe[(size_t)srow * E + col];
                    v = xv + scv * v;
                    split_store(v, Ohi, Olo, (size_t)r * ldp + col);
                }
            }
        }
    }
}

// ---------------------------------------------------------------- flash attention (fp32), writes ctx hi/lo planes
__global__ __launch_bounds__(256) void attn_kernel(const float* __restrict__ qkv,
                                                   bf16* __restrict__ chi,
                                                   bf16* __restrict__ clo) {
    __shared__ float Qs[64][68];
    __shared__ float Ks[64][68];   // reused to hold P after scores
    __shared__ float Vs[64][68];
    const int tid = threadIdx.x;
    const int tx = tid & 15, ty = tid >> 4;
    const int qt = blockIdx.x;       // 16 q tiles
    const int bh = blockIdx.y;       // 128 = b*8+h
    const int b = bh >> 3, h = bh & 7;
    const int lrow = tid >> 4;       // 0..15
    const int lcol = (tid & 15) * 4; // 0..60
#pragma unroll
    for (int p = 0; p < 4; ++p) {
        const int rr = p * 16 + lrow;
        const int q = qt * 64 + rr;
        float4 v = make_float4(0.f, 0.f, 0.f, 0.f);
        if (q < SEQ) v = *(const float4*)(qkv + (size_t)(b * SEQ + q) * 1536 + h * 64 + lcol);
        *(float4*)&Qs[rr][lcol] = v;
    }
    float m_i[4] = {-3e38f, -3e38f, -3e38f, -3e38f};
    float l_i[4] = {0.f, 0.f, 0.f, 0.f};
    float o[4][4] = {};
    for (int kb = 0; kb < SEQ; kb += 64) {
        __syncthreads();
#pragma unroll
        for (int p = 0; p < 4; ++p) {
            const int rr = p * 16 + lrow;
            const int kr = kb + rr;
            float4 kv = make_float4(0.f, 0.f, 0.f, 0.f);
            float4 vv = make_float4(0.f, 0.f, 0.f, 0.f);
            if (kr < SEQ) {
                const float* base = qkv + (size_t)(b * SEQ + kr) * 1536 + h * 64 + lcol;
                kv = *(const float4*)(base + 512);
                vv = *(const float4*)(base + 1024);
            }
            *(float4*)&Ks[rr][lcol] = kv;
            *(float4*)&Vs[rr][lcol] = vv;
        }
        __syncthreads();
        float s[4][4] = {};
#pragma unroll
        for (int d0 = 0; d0 < 64; d0 += 4) {
            float4 qv[4], kv[4];
#pragma unroll
            for (int i = 0; i < 4; ++i) qv[i] = *(const float4*)&Qs[ty * 4 + i][d0];
#pragma unroll
            for (int j = 0; j < 4; ++j) kv[j] = *(const float4*)&Ks[tx * 4 + j][d0];
#pragma unroll
            for (int i = 0; i < 4; ++i)
#pragma unroll
                for (int j = 0; j < 4; ++j)
                    s[i][j] += qv[i].x * kv[j].x + qv[i].y * kv[j].y
                             + qv[i].z * kv[j].z + qv[i].w * kv[j].w;
        }
#pragma unroll
        for (int i = 0; i < 4; ++i) {
            float rm = -3e38f;
#pragma unroll
            for (int j = 0; j < 4; ++j) {
                const int kc = kb + tx * 4 + j;
                s[i][j] = (kc < SEQ) ? s[i][j] * 0.125f : -3e38f;
                rm = fmaxf(rm, s[i][j]);
            }
#pragma unroll
            for (int m = 1; m < 16; m <<= 1) rm = fmaxf(rm, __shfl_xor(rm, m));
            const float mn = fmaxf(m_i[i], rm);
            const float alpha = expf(m_i[i] - mn);
            float rs = 0.f;
#pragma unroll
            for (int j = 0; j < 4; ++j) {
                const float pv = expf(s[i][j] - mn);
                s[i][j] = pv;
                rs += pv;
            }
#pragma unroll
            for (int m = 1; m < 16; m <<= 1) rs += __shfl_xor(rs, m);
            l_i[i] = l_i[i] * alpha + rs;
            m_i[i] = mn;
            o[i][0] *= alpha; o[i][1] *= alpha; o[i][2] *= alpha; o[i][3] *= alpha;
        }
        __syncthreads();
#pragma unroll
        for (int i = 0; i < 4; ++i)
            *(float4*)&Ks[ty * 4 + i][tx * 4] = make_float4(s[i][0], s[i][1], s[i][2], s[i][3]);
        __syncthreads();
#pragma unroll
        for (int k4 = 0; k4 < 64; k4 += 4) {
            float4 pv[4], vv[4];
#pragma unroll
            for (int i = 0; i < 4; ++i) pv[i] = *(const float4*)&Ks[ty * 4 + i][k4];
#pragma unroll
            for (int t = 0; t < 4; ++t) vv[t] = *(const float4*)&Vs[k4 + t][tx * 4];
#pragma unroll
            for (int i = 0; i < 4; ++i) {
                o[i][0] += pv[i].x * vv[0].x + pv[i].y * vv[1].x + pv[i].z * vv[2].x + pv[i].w * vv[3].x;
                o[i][1] += pv[i].x * vv[0].y + pv[i].y * vv[1].y + pv[i].z * vv[2].y + pv[i].w * vv[3].y;
                o[i][2] += pv[i].x * vv[0].z + pv[i].y * vv[1].z + pv[i].z * vv[2].z + pv[i].w * vv[3].z;
                o[i][3] += pv[i].x * vv[0].w + pv[i].y * vv[1].w + pv[i].z * vv[2].w + pv[i].w * vv[3].w;
            }
        }
    }
#pragma unroll
    for (int i = 0; i < 4; ++i) {
        const int q = qt * 64 + ty * 4 + i;
        if (q < SEQ) {
            const float inv = 1.0f / l_i[i];
#pragma unroll
            for (int j = 0; j < 4; ++j) {
                const size_t idx = (size_t)(b * SEQ + q) * E + h * 64 + tx * 4 + j;
                split_store(o[i][j] * inv, chi, clo, idx);
            }
        }
    }
}

// ---------------------------------------------------------------- codebook row norms
__global__ __launch_bounds__(256) void cbnorm_kernel(const float* __restrict__ cb,
                                                     float* __restrict__ out) {
    const int lane = threadIdx.x & 63;
    const int row = blockIdx.x * 4 + (threadIdx.x >> 6);
    const float* p = cb + (size_t)row * E;
    const float4 v0 = *(const float4*)(p + lane * 4);
    const float4 v1 = *(const float4*)(p + 256 + lane * 4);
    float sq = v0.x * v0.x + v0.y * v0.y + v0.z * v0.z + v0.w * v0.w
             + v1.x * v1.x + v1.y * v1.y + v1.z * v1.z + v1.w * v1.w;
#pragma unroll
    for (int m = 1; m < 64; m <<= 1) sq += __shfl_xor(sq, m);
    if (lane == 0) out[row] = sq;
}

// ---------------------------------------------------------------- fused distance+argmin (fp32) over 1024-entry chunk
__global__ __launch_bounds__(256) void argmin_kernel(const float* __restrict__ fc,
                                                     const float* __restrict__ cb,
                                                     const float* __restrict__ cbn,
                                                     float* __restrict__ pbv,
                                                     float* __restrict__ pbi) {
    __shared__ float As[16][72];
    __shared__ float Ws[16][72];
    const int tid = threadIdx.x;
    const int tx = tid & 15, ty = tid >> 4;
    const int rowBase = blockIdx.y * 64;
    const int chunk = blockIdx.x;
    const int lr = tid >> 2;
    const int lk = (tid & 3) << 2;
    float bestv[4] = {3e38f, 3e38f, 3e38f, 3e38f};
    int besti[4] = {0, 0, 0, 0};
    const float* Ap = fc + (size_t)(rowBase + lr) * E + lk;
    for (int ct = 0; ct < 16; ++ct) {
        const int colBase = chunk * 1024 + ct * 64;
        const float* Wp = cb + (size_t)(colBase + lr) * E + lk;
        float acc[4][4] = {};
        for (int k0 = 0; k0 < E; k0 += 16) {
            const float4 a = *(const float4*)(Ap + k0);
            const float4 w = *(const float4*)(Wp + k0);
            __syncthreads();
            As[lk + 0][lr] = a.x; As[lk + 1][lr] = a.y; As[lk + 2][lr] = a.z; As[lk + 3][lr] = a.w;
            Ws[lk + 0][lr] = w.x; Ws[lk + 1][lr] = w.y; Ws[lk + 2][lr] = w.z; Ws[lk + 3][lr] = w.w;
            __syncthreads();
#pragma unroll
            for (int kk = 0; kk < 16; ++kk) {
                const float4 a4 = *(const float4*)&As[kk][ty * 4];
                const float4 b4 = *(const float4*)&Ws[kk][tx * 4];
                const float av[4] = {a4.x, a4.y, a4.z, a4.w};
                const float bvx[4] = {b4.x, b4.y, b4.z, b4.w};
#pragma unroll
                for (int i = 0; i < 4; ++i)
#pragma unroll
                    for (int j = 0; j < 4; ++j)
                        acc[i][j] += av[i] * bvx[j];
            }
        }
        const float4 n4 = *(const float4*)(cbn + colBase + tx * 4);
        const float nv[4] = {n4.x, n4.y, n4.z, n4.w};
#pragma unroll
        for (int i = 0; i < 4; ++i)
#pragma unroll
            for (int j = 0; j < 4; ++j) {
                const float d = nv[j] - 2.0f * acc[i][j];
                const int idx = colBase + tx * 4 + j;
                if (d < bestv[i]) { bestv[i] = d; besti[i] = idx; }
            }
    }
#pragma unroll
    for (int i = 0; i < 4; ++i) {
        float bv = bestv[i];
        int bi = besti[i];
#pragma unroll
        for (int m = 1; m < 16; m <<= 1) {
            const float ov = __shfl_xor(bv, m);
            const int oi = __shfl_xor(bi, m);
            if (ov < bv || (ov == bv && oi < bi)) { bv = ov; bi = oi; }
        }
        if (tx == 0) {
            const int r = rowBase + ty * 4 + i;
            pbv[(size_t)r * 4 + chunk] = bv;
            pbi[(size_t)r * 4 + chunk] = (float)bi;
        }
    }
}

__global__ __launch_bounds__(256) void argmin_combine(const float* __restrict__ pbv,
                                                      const float* __restrict__ pbi,
                                                      float* __restrict__ tokf) {
    const int r = blockIdx.x * 256 + threadIdx.x;
    if (r >= NTOK) return;
    float bv = pbv[(size_t)r * 4];
    float bi = pbi[(size_t)r * 4];
#pragma unroll
    for (int c = 1; c < 4; ++c) {
        const float v = pbv[(size_t)r * 4 + c];
        if (v < bv) { bv = v; bi = pbi[(size_t)r * 4 + c]; }
    }
    tokf[r] = bi;
}

// ---------------------------------------------------------------- launch
extern "C" void kernel_launch(void* const* d_in, const int* in_sizes, int n_in,
                              void* d_out, int out_size, void* d_ws, size_t ws_size,
                              hipStream_t stream) {
    const int* noisy = (const int*)d_in[0];
    const float* codebook = (const float*)d_in[1];
    const float* pos_enc = (const float*)d_in[2];
    const float* qkv_w = (const float*)d_in[3];
    const float* qkv_b = (const float*)d_in[4];
    const float* out_w = (const float*)d_in[5];
    const float* out_b = (const float*)d_in[6];
    const float* ln1_g = (const float*)d_in[7];
    const float* ln1_b = (const float*)d_in[8];
    const float* ln2_g = (const float*)d_in[9];
    const float* ln2_b = (const float*)d_in[10];
    const float* ff1_w = (const float*)d_in[11];
    const float* ff1_b = (const float*)d_in[12];
    const float* ff2_w = (const float*)d_in[13];
    const float* ff2_b = (const float*)d_in[14];
    const float* fin_g = (const float*)d_in[15];
    const float* fin_b = (const float*)d_in[16];
    const float* pp1_w = (const float*)d_in[17];
    const float* pp1_b = (const float*)d_in[18];
    const float* pp_ln_g = (const float*)d_in[19];
    const float* pp_ln_b = (const float*)d_in[20];
    const float* pp2_w = (const float*)d_in[21];
    const float* pp2_b = (const float*)d_in[22];
    const float* res_w = (const float*)d_in[23];
    const float* fc1_w = (const float*)d_in[24];
    const float* fc1_b = (const float*)d_in[25];
    const float* fc_ln_g = (const float*)d_in[26];
    const float* fc_ln_b = (const float*)d_in[27];
    const float* fc2_w = (const float*)d_in[28];
    const float* fc2_b = (const float*)d_in[29];

    // workspace (floats), total ~35.0M floats = 140 MB
    float* ws = (float*)d_ws;
    float* y = ws;                        // [0, 8.192M)
    float* REG = ws + 8192000;            // [8.192M, 32.768M)  24.576M floats
    // REG usage: per-layer qkv fp32 (24.576M) | ff mid planes (16.384M) | tail slots
    float* qkv = REG;
    bf16* mid_hi = (bf16*)REG;                       // 16000x1024 bf16
    bf16* mid_lo = (bf16*)(REG + 8192000);
    float* slotA = REG;                   // tail: e-planes / fc
    float* slotB = REG + 8192000;         // tail: pp1/fc1 fp32 tmp
    bf16* e_hi = (bf16*)slotA;
    bf16* e_lo = (bf16*)slotA + 8192000;
    // weight split buffers
    bf16* wA_hi = (bf16*)(ws + 32768000);  // cap 2048x512
    bf16* wA_lo = wA_hi + 1048576;
    bf16* wB_hi = wA_lo + 1048576;
    bf16* wB_lo = wB_hi + 1048576;
    float* cbn = ws + 34865152;
    float* pbv = ws + 34869248;
    float* pbi = ws + 34933248;
    // h planes live in d_out (dead before final outputs are written)
    bf16* h_hi = (bf16*)d_out;
    bf16* h_lo = h_hi + 8192000;
    float* tokf = (float*)d_out + 8192000;

    const dim3 blk(256);
    const dim3 g512(4, 125), g1024(8, 125), g1536(12, 125);

    embed_kernel<<<dim3(NTOK), dim3(128), 0, stream>>>(noisy, codebook, pos_enc, y);
    cbnorm_kernel<<<dim3(1024), blk, 0, stream>>>(codebook, cbn);

    for (int l = 0; l < 4; ++l) {
        ln_planes<0><<<dim3(4000), blk, 0, stream>>>(y, h_hi, h_lo, ln1_g + l * E, ln1_b + l * E);
        split_w<<<dim3(3072), blk, 0, stream>>>(qkv_w + (size_t)l * 1536 * E, E, 9, 1536 * E, wA_hi, wA_lo);
        gemm_split<0><<<g1536, blk, 0, stream>>>(
            h_hi, h_lo, E, wA_hi, wA_lo, E, qkv_b + (size_t)l * 1536,
            qkv, 1536, nullptr, nullptr, 0, nullptr, nullptr, nullptr, nullptr, E);
        attn_kernel<<<dim3(16, 128), blk, 0, stream>>>(qkv, h_hi, h_lo);  // ctx -> h planes
        split_w<<<dim3(1024), blk, 0, stream>>>(out_w + (size_t)l * E * E, E, 9, E * E, wB_hi, wB_lo);
        gemm_split<1><<<g512, blk, 0, stream>>>(
            h_hi, h_lo, E, wB_hi, wB_lo, E, out_b + (size_t)l * E,
            y, E, nullptr, nullptr, 0, nullptr, nullptr, nullptr, nullptr, E);
        ln_planes<0><<<dim3(4000), blk, 0, stream>>>(y, h_hi, h_lo, ln2_g + l * E, ln2_b + l * E);
        split_w<<<dim3(4096), blk, 0, stream>>>(ff1_w + (size_t)l * FFD * E, E, 9, FFD * E, wA_hi, wA_lo);
        split_w<<<dim3(4096), blk, 0, stream>>>(ff2_w + (size_t)l * E * FFD, FFD, 11, E * FFD, wB_hi, wB_lo);
        for (int c = 0; c < 2; ++c) {
            gemm_split<2><<<g1024, blk, 0, stream>>>(
                h_hi, h_lo, E, wA_hi + (size_t)c * 1024 * E, wA_lo + (size_t)c * 1024 * E, E,
                ff1_b + (size_t)l * FFD + c * 1024,
                nullptr, 0, mid_hi, mid_lo, 1024, nullptr, nullptr, nullptr, nullptr, E);
            gemm_split<1><<<g512, blk, 0, stream>>>(
                mid_hi, mid_lo, 1024, wB_hi + c * 1024, wB_lo + c * 1024, FFD,
                (c == 0) ? (ff2_b + (size_t)l * E) : nullptr,
                y, E, nullptr, nullptr, 0, nullptr, nullptr, nullptr, nullptr, 1024);
        }
    }

    // tail
    ln_planes<0><<<dim3(4000), blk, 0, stream>>>(y, h_hi, h_lo, fin_g, fin_b);
    split_w<<<dim3(1024), blk, 0, stream>>>(pp1_w, E, 9, E * E, wA_hi, wA_lo);
    gemm_split<0><<<g512, blk, 0, stream>>>(
        h_hi, h_lo, E, wA_hi, wA_lo, E, pp1_b,
        slotB, E, nullptr, nullptr, 0, nullptr, nullptr, nullptr, nullptr, E);
    ln_planes<1><<<dim3(4000), blk, 0, stream>>>(slotB, h_hi, h_lo, pp_ln_g, pp_ln_b);
    split_w<<<dim3(1024), blk, 0, stream>>>(pp2_w, E, 9, E * E, wB_hi, wB_lo);
    // enhanced = emb(r,c) + res_w*(h@pp2^T + b) -> e planes (slotA)
    gemm_split<3><<<g512, blk, 0, stream>>>(
        h_hi, h_lo, E, wB_hi, wB_lo, E, pp2_b,
        nullptr, 0, e_hi, e_lo, E, noisy, codebook, pos_enc, res_w, E);
    split_w<<<dim3(1024), blk, 0, stream>>>(fc1_w, E, 9, E * E, wA_hi, wA_lo);
    gemm_split<0><<<g512, blk, 0, stream>>>(
        e_hi, e_lo, E, wA_hi, wA_lo, E, fc1_b,
        slotB, E, nullptr, nullptr, 0, nullptr, nullptr, nullptr, nullptr, E);
    ln_planes<1><<<dim3(4000), blk, 0, stream>>>(slotB, h_hi, h_lo, fc_ln_g, fc_ln_b);
    split_w<<<dim3(1024), blk, 0, stream>>>(fc2_w, E, 9, E * E, wB_hi, wB_lo);
    gemm_split<0><<<g512, blk, 0, stream>>>(
        h_hi, h_lo, E, wB_hi, wB_lo, E, fc2_b,
        slotA, E, nullptr, nullptr, 0, nullptr, nullptr, nullptr, nullptr, E);   // fc -> slotA

    argmin_kernel<<<dim3(4, 250), blk, 0, stream>>>(slotA, codebook, cbn, pbv, pbi);
    argmin_combine<<<dim3(63), blk, 0, stream>>>(pbv, pbi, tokf);
    hipMemcpyAsync(d_out, slotA, (size_t)8192000 * 4, hipMemcpyDeviceToDevice, stream);
}

// Round 4
// 4377.053 us; speedup vs baseline: 3.1988x; 2.2435x over previous
//
#include <hip/hip_runtime.h>
#include <hip/hip_bf16.h>
#include <math.h>

#define NTOK 16000
#define E    512
#define FFD  2048
#define CBN  4096
#define SEQ  1000
#define NH   8
#define VLD  1008   // Vt padded leading dim (s), multiple of 8

typedef __hip_bfloat16 bf16;
typedef __attribute__((ext_vector_type(8))) short short8;
typedef __attribute__((ext_vector_type(4))) float f32x4;

__device__ __forceinline__ float gelu_f(float v) {
    return 0.5f * v * (1.0f + erff(v * 0.70710678118654752f));
}

__device__ __forceinline__ void split_store(float v, bf16* hi, bf16* lo, size_t idx) {
    bf16 h = __float2bfloat16(v);
    hi[idx] = h;
    lo[idx] = __float2bfloat16(v - __bfloat162float(h));
}

// ---------------------------------------------------------------- embed -> y (fp32)
__global__ __launch_bounds__(128) void embed_kernel(const int* __restrict__ tok,
                                                    const float* __restrict__ cb,
                                                    const float* __restrict__ pe,
                                                    float* __restrict__ y) {
    const int row = blockIdx.x;
    const int s = row % SEQ;
    const int t = tok[row];
    const int c = threadIdx.x * 4;
    const float4 cv = *(const float4*)(cb + (size_t)t * E + c);
    const float4 pv = *(const float4*)(pe + (size_t)s * E + c);
    *(float4*)(y + (size_t)row * E + c) =
        make_float4(cv.x + pv.x, cv.y + pv.y, cv.z + pv.z, cv.w + pv.w);
}

// ---------------------------------------------------------------- weight split fp32 -> hi/lo bf16 (compact dst)
__global__ __launch_bounds__(256) void split_w(const float* __restrict__ src, int ld,
                                               int cols_log2, int n,
                                               bf16* __restrict__ hi, bf16* __restrict__ lo) {
    const int i = blockIdx.x * 256 + threadIdx.x;
    if (i >= n) return;
    const int r = i >> cols_log2;
    const int c = i & ((1 << cols_log2) - 1);
    const float v = src[(size_t)r * ld + c];
    split_store(v, hi, lo, i);
}

// ---------------------------------------------------------------- layernorm -> hi/lo planes (1 wave/row)
template<int GELU>
__global__ __launch_bounds__(256) void ln_planes(const float* __restrict__ in,
                                                 bf16* __restrict__ hi, bf16* __restrict__ lo,
                                                 const float* __restrict__ g,
                                                 const float* __restrict__ b) {
    const int lane = threadIdx.x & 63;
    const int row = blockIdx.x * 4 + (threadIdx.x >> 6);
    const float* p = in + (size_t)row * E;
    const float4 v0 = *(const float4*)(p + lane * 4);
    const float4 v1 = *(const float4*)(p + 256 + lane * 4);
    float sum = v0.x + v0.y + v0.z + v0.w + v1.x + v1.y + v1.z + v1.w;
    float sq = v0.x * v0.x + v0.y * v0.y + v0.z * v0.z + v0.w * v0.w
             + v1.x * v1.x + v1.y * v1.y + v1.z * v1.z + v1.w * v1.w;
#pragma unroll
    for (int m = 1; m < 64; m <<= 1) {
        sum += __shfl_xor(sum, m);
        sq += __shfl_xor(sq, m);
    }
    const float mean = sum * (1.0f / 512.0f);
    const float var = sq * (1.0f / 512.0f) - mean * mean;
    const float rstd = rsqrtf(var + 1e-5f);
    const float4 g0 = *(const float4*)(g + lane * 4);
    const float4 g1 = *(const float4*)(g + 256 + lane * 4);
    const float4 b0 = *(const float4*)(b + lane * 4);
    const float4 b1 = *(const float4*)(b + 256 + lane * 4);
    const size_t base = (size_t)row * E;
    float o;
    const float vv0[4] = {v0.x, v0.y, v0.z, v0.w};
    const float gg0[4] = {g0.x, g0.y, g0.z, g0.w};
    const float bb0[4] = {b0.x, b0.y, b0.z, b0.w};
    const float vv1[4] = {v1.x, v1.y, v1.z, v1.w};
    const float gg1[4] = {g1.x, g1.y, g1.z, g1.w};
    const float bb1[4] = {b1.x, b1.y, b1.z, b1.w};
#pragma unroll
    for (int t = 0; t < 4; ++t) {
        o = (vv0[t] - mean) * rstd * gg0[t] + bb0[t];
        if (GELU) o = gelu_f(o);
        split_store(o, hi, lo, base + lane * 4 + t);
        o = (vv1[t] - mean) * rstd * gg1[t] + bb1[t];
        if (GELU) o = gelu_f(o);
        split_store(o, hi, lo, base + 256 + lane * 4 + t);
    }
}

// ---------------------------------------------------------------- split-bf16 MFMA NT GEMM
// C[M,N] = A[M,:]·W[N,:]^T via AhWh + AhWl + AlWh
// 128x128 tile, BK=32, 256 threads = 4 waves (2x2 of 64x64)
// OUT: 0 = C fp32 (+bias); 1 = C += (+bias); 2 = gelu -> planes;
//      3 = emb(r,c) + resw*(v+bias) -> planes; 4 = plain -> planes
template<int OUT>
__global__ __launch_bounds__(256) void gemm_split(
    const bf16* __restrict__ Ah, const bf16* __restrict__ Al, int lda,
    const bf16* __restrict__ Wh, const bf16* __restrict__ Wl, int ldw,
    const float* __restrict__ bias,
    float* __restrict__ C, int ldc,
    bf16* __restrict__ Ohi, bf16* __restrict__ Olo, int ldp,
    const int* __restrict__ noisy, const float* __restrict__ cb,
    const float* __restrict__ pe, const float* __restrict__ resw,
    int K) {
    __shared__ short Ash[2][128][40];   // [plane][row][k + 8 pad]
    __shared__ short Wsh[2][128][40];
    const int tid = threadIdx.x;
    const int rowBase = blockIdx.y * 128;
    const int colBase = blockIdx.x * 128;
    const int wave = tid >> 6, lane = tid & 63;
    const int wm = (wave & 1) * 64, wn = (wave >> 1) * 64;
    const int lm = lane & 15;
    const int q8 = (lane >> 4) * 8;
    const int r0 = tid >> 2;          // 0..63
    const int kq = (tid & 3) * 8;     // 0,8,16,24

    f32x4 acc[4][4];
#pragma unroll
    for (int i = 0; i < 4; ++i)
#pragma unroll
        for (int j = 0; j < 4; ++j)
            acc[i][j] = (f32x4){0.f, 0.f, 0.f, 0.f};

    for (int k0 = 0; k0 < K; k0 += 32) {
        __syncthreads();
        {
            const size_t a0 = (size_t)(rowBase + r0) * lda + k0 + kq;
            const size_t a1 = (size_t)(rowBase + r0 + 64) * lda + k0 + kq;
            const size_t w0 = (size_t)(colBase + r0) * ldw + k0 + kq;
            const size_t w1 = (size_t)(colBase + r0 + 64) * ldw + k0 + kq;
            *(short8*)&Ash[0][r0][kq]      = *(const short8*)(Ah + a0);
            *(short8*)&Ash[0][r0 + 64][kq] = *(const short8*)(Ah + a1);
            *(short8*)&Ash[1][r0][kq]      = *(const short8*)(Al + a0);
            *(short8*)&Ash[1][r0 + 64][kq] = *(const short8*)(Al + a1);
            *(short8*)&Wsh[0][r0][kq]      = *(const short8*)(Wh + w0);
            *(short8*)&Wsh[0][r0 + 64][kq] = *(const short8*)(Wh + w1);
            *(short8*)&Wsh[1][r0][kq]      = *(const short8*)(Wl + w0);
            *(short8*)&Wsh[1][r0 + 64][kq] = *(const short8*)(Wl + w1);
        }
        __syncthreads();
        short8 ah[4], al[4], wh[4], wl[4];
#pragma unroll
        for (int i = 0; i < 4; ++i) {
            ah[i] = *(const short8*)&Ash[0][wm + i * 16 + lm][q8];
            al[i] = *(const short8*)&Ash[1][wm + i * 16 + lm][q8];
            wh[i] = *(const short8*)&Wsh[0][wn + i * 16 + lm][q8];
            wl[i] = *(const short8*)&Wsh[1][wn + i * 16 + lm][q8];
        }
#pragma unroll
        for (int i = 0; i < 4; ++i)
#pragma unroll
            for (int j = 0; j < 4; ++j)
                acc[i][j] = __builtin_amdgcn_mfma_f32_16x16x32_bf16(ah[i], wh[j], acc[i][j], 0, 0, 0);
#pragma unroll
        for (int i = 0; i < 4; ++i)
#pragma unroll
            for (int j = 0; j < 4; ++j)
                acc[i][j] = __builtin_amdgcn_mfma_f32_16x16x32_bf16(ah[i], wl[j], acc[i][j], 0, 0, 0);
#pragma unroll
        for (int i = 0; i < 4; ++i)
#pragma unroll
            for (int j = 0; j < 4; ++j)
                acc[i][j] = __builtin_amdgcn_mfma_f32_16x16x32_bf16(al[i], wh[j], acc[i][j], 0, 0, 0);
    }

    // epilogue: C/D layout col = lane&15, row = (lane>>4)*4 + reg
    float bv[4];
#pragma unroll
    for (int j = 0; j < 4; ++j)
        bv[j] = bias ? bias[colBase + wn + j * 16 + lm] : 0.f;
    float scv = 0.f;
    if (OUT == 3) scv = resw[0];
#pragma unroll
    for (int i = 0; i < 4; ++i) {
#pragma unroll
        for (int reg = 0; reg < 4; ++reg) {
            const int r = rowBase + wm + i * 16 + (lane >> 4) * 4 + reg;
            int tok = 0, srow = 0;
            if (OUT == 3) { tok = noisy[r]; srow = r % SEQ; }
#pragma unroll
            for (int j = 0; j < 4; ++j) {
                const int col = colBase + wn + j * 16 + lm;
                float v = acc[i][j][reg] + bv[j];
                if (OUT == 0) {
                    C[(size_t)r * ldc + col] = v;
                } else if (OUT == 1) {
                    float* cp = C + (size_t)r * ldc + col;
                    *cp = *cp + v;
                } else if (OUT == 2) {
                    v = gelu_f(v);
                    split_store(v, Ohi, Olo, (size_t)r * ldp + col);
                } else if (OUT == 3) {
                    const float xv = cb[(size_t)tok * E + col] + pe[(size_t)srow * E + col];
                    v = xv + scv * v;
                    split_store(v, Ohi, Olo, (size_t)r * ldp + col);
                } else { // OUT == 4
                    split_store(v, Ohi, Olo, (size_t)r * ldp + col);
                }
            }
        }
    }
}

// ---------------------------------------------------------------- V transpose: qkv planes -> Vt[bh*64+d][s] (ld VLD)
__global__ __launch_bounds__(256) void vtrans(const bf16* __restrict__ vh_src,
                                              const bf16* __restrict__ vl_src,
                                              bf16* __restrict__ vth,
                                              bf16* __restrict__ vtl) {
    __shared__ short T[64][72];
    const int tid = threadIdx.x;
    const int st = blockIdx.x;   // 16 s-tiles of 64
    const int bh = blockIdx.y;   // 128
    const int b = bh >> 3, h = bh & 7;
    const int sr = tid >> 2, dq = (tid & 3) * 16;
    const int s_g = st * 64 + sr;
    const int od = tid >> 3;          // 0..31 (+32)
    const int osq = (tid & 7) * 8;    // 0..56
#pragma unroll
    for (int p = 0; p < 2; ++p) {
        const short* src = (const short*)(p ? vl_src : vh_src);
        short* dst = (short*)(p ? vtl : vth);
        short8 a0 = {0, 0, 0, 0, 0, 0, 0, 0};
        short8 a1 = {0, 0, 0, 0, 0, 0, 0, 0};
        if (s_g < SEQ) {
            const short* sp = src + (size_t)(b * SEQ + s_g) * 1536 + 1024 + h * 64 + dq;
            a0 = *(const short8*)sp;
            a1 = *(const short8*)(sp + 8);
        }
        __syncthreads();
#pragma unroll
        for (int j = 0; j < 8; ++j) T[dq + j][sr] = a0[j];
#pragma unroll
        for (int j = 0; j < 8; ++j) T[dq + 8 + j][sr] = a1[j];
        __syncthreads();
        const int scol = st * 64 + osq;
        if (scol + 8 <= VLD) {
            const short8 o0 = *(const short8*)&T[od][osq];
            const short8 o1 = *(const short8*)&T[od + 32][osq];
            *(short8*)(dst + (size_t)(bh * 64 + od) * VLD + scol) = o0;
            *(short8*)(dst + (size_t)(bh * 64 + od + 32) * VLD + scol) = o1;
        }
    }
}

// ---------------------------------------------------------------- MFMA flash attention (split bf16)
// grid (16 q-tiles, 128 bh), 256 thr = 4 waves, each wave 16 q-rows
__global__ __launch_bounds__(256) void attn_mfma(const bf16* __restrict__ qkh,
                                                 const bf16* __restrict__ qkl,
                                                 const bf16* __restrict__ vth,
                                                 const bf16* __restrict__ vtl,
                                                 bf16* __restrict__ chi,
                                                 bf16* __restrict__ clo) {
    __shared__ short QPs[2][64][72];   // Q staging, then P (both intra-wave bands)
    __shared__ short Ks[2][64][72];
    __shared__ short Vs[2][64][72];    // Vt tile: [d][n]
    const int tid = threadIdx.x;
    const int qt = blockIdx.x, bh = blockIdx.y;
    const int b = bh >> 3, h = bh & 7;
    const int wave = tid >> 6, lane = tid & 63;
    const int lm = lane & 15, g = lane >> 4, q8 = g * 8;
    const int wq = wave * 16;
    const int r0 = tid >> 2, kq = (tid & 3) * 16;

    // stage Q (each wave stages its own 16-row band)
    {
        const int q = qt * 64 + r0;
        short8 z = {0, 0, 0, 0, 0, 0, 0, 0};
        short8 a0 = z, a1 = z, b0 = z, b1 = z;
        if (q < SEQ) {
            const size_t base = (size_t)(b * SEQ + q) * 1536 + h * 64 + kq;
            a0 = *(const short8*)((const short*)qkh + base);
            a1 = *(const short8*)((const short*)qkh + base + 8);
            b0 = *(const short8*)((const short*)qkl + base);
            b1 = *(const short8*)((const short*)qkl + base + 8);
        }
        *(short8*)&QPs[0][r0][kq] = a0; *(short8*)&QPs[0][r0][kq + 8] = a1;
        *(short8*)&QPs[1][r0][kq] = b0; *(short8*)&QPs[1][r0][kq + 8] = b1;
    }
    __syncthreads();
    short8 qfh[2], qfl[2];
#pragma unroll
    for (int t = 0; t < 2; ++t) {
        qfh[t] = *(const short8*)&QPs[0][wq + lm][t * 32 + q8];
        qfl[t] = *(const short8*)&QPs[1][wq + lm][t * 32 + q8];
    }

    float m_i[4] = {-3e38f, -3e38f, -3e38f, -3e38f};
    float l_i[4] = {0.f, 0.f, 0.f, 0.f};
    f32x4 o[4];
#pragma unroll
    for (int dt = 0; dt < 4; ++dt) o[dt] = (f32x4){0.f, 0.f, 0.f, 0.f};

    for (int kb = 0; kb < SEQ; kb += 64) {
        __syncthreads();
        // stage K and Vt tile
        {
            const int kr = kb + r0;
            short8 z = {0, 0, 0, 0, 0, 0, 0, 0};
            short8 a0 = z, a1 = z, b0 = z, b1 = z;
            if (kr < SEQ) {
                const size_t base = (size_t)(b * SEQ + kr) * 1536 + 512 + h * 64 + kq;
                a0 = *(const short8*)((const short*)qkh + base);
                a1 = *(const short8*)((const short*)qkh + base + 8);
                b0 = *(const short8*)((const short*)qkl + base);
                b1 = *(const short8*)((const short*)qkl + base + 8);
            }
            *(short8*)&Ks[0][r0][kq] = a0; *(short8*)&Ks[0][r0][kq + 8] = a1;
            *(short8*)&Ks[1][r0][kq] = b0; *(short8*)&Ks[1][r0][kq + 8] = b1;
            const size_t vbase = (size_t)(bh * 64 + r0) * VLD + kb + kq;
            short8 v0 = z, v1 = z, w0 = z, w1 = z;
            if (kb + kq + 8 <= VLD) {
                v0 = *(const short8*)((const short*)vth + vbase);
                w0 = *(const short8*)((const short*)vtl + vbase);
            }
            if (kb + kq + 16 <= VLD) {
                v1 = *(const short8*)((const short*)vth + vbase + 8);
                w1 = *(const short8*)((const short*)vtl + vbase + 8);
            }
            *(short8*)&Vs[0][r0][kq] = v0; *(short8*)&Vs[0][r0][kq + 8] = v1;
            *(short8*)&Vs[1][r0][kq] = w0; *(short8*)&Vs[1][r0][kq + 8] = w1;
        }
        __syncthreads();
        // scores: 4 n-tiles
        f32x4 sac[4];
#pragma unroll
        for (int j = 0; j < 4; ++j) sac[j] = (f32x4){0.f, 0.f, 0.f, 0.f};
#pragma unroll
        for (int t = 0; t < 2; ++t) {
#pragma unroll
            for (int j = 0; j < 4; ++j) {
                const short8 kh = *(const short8*)&Ks[0][j * 16 + lm][t * 32 + q8];
                const short8 kl = *(const short8*)&Ks[1][j * 16 + lm][t * 32 + q8];
                sac[j] = __builtin_amdgcn_mfma_f32_16x16x32_bf16(qfh[t], kh, sac[j], 0, 0, 0);
                sac[j] = __builtin_amdgcn_mfma_f32_16x16x32_bf16(qfh[t], kl, sac[j], 0, 0, 0);
                sac[j] = __builtin_amdgcn_mfma_f32_16x16x32_bf16(qfl[t], kh, sac[j], 0, 0, 0);
            }
        }
        // online softmax, P -> QPs (intra-wave band)
        float alpha_v[4];
#pragma unroll
        for (int reg = 0; reg < 4; ++reg) {
            float sv[4];
            float rm = -3e38f;
#pragma unroll
            for (int j = 0; j < 4; ++j) {
                const int kc = kb + j * 16 + lm;
                float s = sac[j][reg] * 0.125f;
                s = (kc < SEQ) ? s : -3e38f;
                sv[j] = s;
                rm = fmaxf(rm, s);
            }
#pragma unroll
            for (int m = 1; m < 16; m <<= 1) rm = fmaxf(rm, __shfl_xor(rm, m));
            const float mn = fmaxf(m_i[reg], rm);
            const float al = expf(m_i[reg] - mn);
            float rs = 0.f;
            const int prow = wq + g * 4 + reg;
#pragma unroll
            for (int j = 0; j < 4; ++j) {
                const float pv = expf(sv[j] - mn);
                rs += pv;
                bf16 phb = __float2bfloat16(pv);
                bf16 plb = __float2bfloat16(pv - __bfloat162float(phb));
                QPs[0][prow][j * 16 + lm] = *reinterpret_cast<short*>(&phb);
                QPs[1][prow][j * 16 + lm] = *reinterpret_cast<short*>(&plb);
            }
#pragma unroll
            for (int m = 1; m < 16; m <<= 1) rs += __shfl_xor(rs, m);
            l_i[reg] = l_i[reg] * al + rs;
            m_i[reg] = mn;
            alpha_v[reg] = al;
        }
        const f32x4 av = {alpha_v[0], alpha_v[1], alpha_v[2], alpha_v[3]};
#pragma unroll
        for (int dt = 0; dt < 4; ++dt) o[dt] *= av;
        __syncthreads();   // P visibility safety (uniform control flow)
        // PV: contraction over n (2 k-steps)
#pragma unroll
        for (int t = 0; t < 2; ++t) {
            const short8 ph = *(const short8*)&QPs[0][wq + lm][t * 32 + q8];
            const short8 pl = *(const short8*)&QPs[1][wq + lm][t * 32 + q8];
#pragma unroll
            for (int dt = 0; dt < 4; ++dt) {
                const short8 vh = *(const short8*)&Vs[0][dt * 16 + lm][t * 32 + q8];
                const short8 vl = *(const short8*)&Vs[1][dt * 16 + lm][t * 32 + q8];
                o[dt] = __builtin_amdgcn_mfma_f32_16x16x32_bf16(ph, vh, o[dt], 0, 0, 0);
                o[dt] = __builtin_amdgcn_mfma_f32_16x16x32_bf16(ph, vl, o[dt], 0, 0, 0);
                o[dt] = __builtin_amdgcn_mfma_f32_16x16x32_bf16(pl, vh, o[dt], 0, 0, 0);
            }
        }
    }
    // epilogue -> ctx planes
#pragma unroll
    for (int reg = 0; reg < 4; ++reg) {
        const int q = qt * 64 + wq + g * 4 + reg;
        if (q < SEQ) {
            const float inv = 1.0f / l_i[reg];
#pragma unroll
            for (int dt = 0; dt < 4; ++dt) {
                const size_t idx = (size_t)(b * SEQ + q) * E + h * 64 + dt * 16 + lm;
                split_store(o[dt][reg] * inv, chi, clo, idx);
            }
        }
    }
}

// ---------------------------------------------------------------- codebook row norms
__global__ __launch_bounds__(256) void cbnorm_kernel(const float* __restrict__ cb,
                                                     float* __restrict__ out) {
    const int lane = threadIdx.x & 63;
    const int row = blockIdx.x * 4 + (threadIdx.x >> 6);
    const float* p = cb + (size_t)row * E;
    const float4 v0 = *(const float4*)(p + lane * 4);
    const float4 v1 = *(const float4*)(p + 256 + lane * 4);
    float sq = v0.x * v0.x + v0.y * v0.y + v0.z * v0.z + v0.w * v0.w
             + v1.x * v1.x + v1.y * v1.y + v1.z * v1.z + v1.w * v1.w;
#pragma unroll
    for (int m = 1; m < 64; m <<= 1) sq += __shfl_xor(sq, m);
    if (lane == 0) out[row] = sq;
}

// ---------------------------------------------------------------- fused distance+argmin (fp32) over 1024-entry chunk
__global__ __launch_bounds__(256) void argmin_kernel(const float* __restrict__ fc,
                                                     const float* __restrict__ cb,
                                                     const float* __restrict__ cbn,
                                                     float* __restrict__ pbv,
                                                     float* __restrict__ pbi) {
    __shared__ float As[16][72];
    __shared__ float Ws[16][72];
    const int tid = threadIdx.x;
    const int tx = tid & 15, ty = tid >> 4;
    const int rowBase = blockIdx.y * 64;
    const int chunk = blockIdx.x;
    const int lr = tid >> 2;
    const int lk = (tid & 3) << 2;
    float bestv[4] = {3e38f, 3e38f, 3e38f, 3e38f};
    int besti[4] = {0, 0, 0, 0};
    const float* Ap = fc + (size_t)(rowBase + lr) * E + lk;
    for (int ct = 0; ct < 16; ++ct) {
        const int colBase = chunk * 1024 + ct * 64;
        const float* Wp = cb + (size_t)(colBase + lr) * E + lk;
        float acc[4][4] = {};
        for (int k0 = 0; k0 < E; k0 += 16) {
            const float4 a = *(const float4*)(Ap + k0);
            const float4 w = *(const float4*)(Wp + k0);
            __syncthreads();
            As[lk + 0][lr] = a.x; As[lk + 1][lr] = a.y; As[lk + 2][lr] = a.z; As[lk + 3][lr] = a.w;
            Ws[lk + 0][lr] = w.x; Ws[lk + 1][lr] = w.y; Ws[lk + 2][lr] = w.z; Ws[lk + 3][lr] = w.w;
            __syncthreads();
#pragma unroll
            for (int kk = 0; kk < 16; ++kk) {
                const float4 a4 = *(const float4*)&As[kk][ty * 4];
                const float4 b4 = *(const float4*)&Ws[kk][tx * 4];
                const float avv[4] = {a4.x, a4.y, a4.z, a4.w};
                const float bvx[4] = {b4.x, b4.y, b4.z, b4.w};
#pragma unroll
                for (int i = 0; i < 4; ++i)
#pragma unroll
                    for (int j = 0; j < 4; ++j)
                        acc[i][j] += avv[i] * bvx[j];
            }
        }
        const float4 n4 = *(const float4*)(cbn + colBase + tx * 4);
        const float nv[4] = {n4.x, n4.y, n4.z, n4.w};
#pragma unroll
        for (int i = 0; i < 4; ++i)
#pragma unroll
            for (int j = 0; j < 4; ++j) {
                const float d = nv[j] - 2.0f * acc[i][j];
                const int idx = colBase + tx * 4 + j;
                if (d < bestv[i]) { bestv[i] = d; besti[i] = idx; }
            }
    }
#pragma unroll
    for (int i = 0; i < 4; ++i) {
        float bv = bestv[i];
        int bi = besti[i];
#pragma unroll
        for (int m = 1; m < 16; m <<= 1) {
            const float ov = __shfl_xor(bv, m);
            const int oi = __shfl_xor(bi, m);
            if (ov < bv || (ov == bv && oi < bi)) { bv = ov; bi = oi; }
        }
        if (tx == 0) {
            const int r = rowBase + ty * 4 + i;
            pbv[(size_t)r * 4 + chunk] = bv;
            pbi[(size_t)r * 4 + chunk] = (float)bi;
        }
    }
}

__global__ __launch_bounds__(256) void argmin_combine(const float* __restrict__ pbv,
                                                      const float* __restrict__ pbi,
                                                      float* __restrict__ tokf) {
    const int r = blockIdx.x * 256 + threadIdx.x;
    if (r >= NTOK) return;
    float bv = pbv[(size_t)r * 4];
    float bi = pbi[(size_t)r * 4];
#pragma unroll
    for (int c = 1; c < 4; ++c) {
        const float v = pbv[(size_t)r * 4 + c];
        if (v < bv) { bv = v; bi = pbi[(size_t)r * 4 + c]; }
    }
    tokf[r] = bi;
}

// ---------------------------------------------------------------- launch
extern "C" void kernel_launch(void* const* d_in, const int* in_sizes, int n_in,
                              void* d_out, int out_size, void* d_ws, size_t ws_size,
                              hipStream_t stream) {
    const int* noisy = (const int*)d_in[0];
    const float* codebook = (const float*)d_in[1];
    const float* pos_enc = (const float*)d_in[2];
    const float* qkv_w = (const float*)d_in[3];
    const float* qkv_b = (const float*)d_in[4];
    const float* out_w = (const float*)d_in[5];
    const float* out_b = (const float*)d_in[6];
    const float* ln1_g = (const float*)d_in[7];
    const float* ln1_b = (const float*)d_in[8];
    const float* ln2_g = (const float*)d_in[9];
    const float* ln2_b = (const float*)d_in[10];
    const float* ff1_w = (const float*)d_in[11];
    const float* ff1_b = (const float*)d_in[12];
    const float* ff2_w = (const float*)d_in[13];
    const float* ff2_b = (const float*)d_in[14];
    const float* fin_g = (const float*)d_in[15];
    const float* fin_b = (const float*)d_in[16];
    const float* pp1_w = (const float*)d_in[17];
    const float* pp1_b = (const float*)d_in[18];
    const float* pp_ln_g = (const float*)d_in[19];
    const float* pp_ln_b = (const float*)d_in[20];
    const float* pp2_w = (const float*)d_in[21];
    const float* pp2_b = (const float*)d_in[22];
    const float* res_w = (const float*)d_in[23];
    const float* fc1_w = (const float*)d_in[24];
    const float* fc1_b = (const float*)d_in[25];
    const float* fc_ln_g = (const float*)d_in[26];
    const float* fc_ln_b = (const float*)d_in[27];
    const float* fc2_w = (const float*)d_in[28];
    const float* fc2_b = (const float*)d_in[29];

    // workspace (floats), total 41,025,536 floats = 164.1 MB
    float* ws = (float*)d_ws;
    float* y = ws;                        // [0, 8.192M)
    float* REG = ws + 8192000;            // [8.192M, 32.768M)
    bf16* qkvh = (bf16*)REG;              // 16000x1536 shorts
    bf16* qkvl = qkvh + 24576000;
    bf16* mid_hi = (bf16*)REG;            // FF phase: 16000x1024
    bf16* mid_lo = mid_hi + 16384000;
    float* slotA = REG;                   // tail: e planes / fc fp32
    float* slotB = REG + 8192000;         // tail: pp1/fc1 fp32 tmp, then cbn/pbv/pbi
    bf16* e_hi = (bf16*)slotA;
    bf16* e_lo = e_hi + 8192000;
    float* WV = ws + 32768000;            // [32.768M, 41.0255M): Vt planes OR weight splits
    bf16* vth = (bf16*)WV;                // 8192 x VLD
    bf16* vtl = vth + 8192 * VLD;
    bf16* wA_hi = (bf16*)WV;              // cap 2048x512 each
    bf16* wA_lo = wA_hi + 1048576;
    bf16* wB_hi = wA_lo + 1048576;
    bf16* wB_lo = wB_hi + 1048576;
    float* cbn = slotB;                   // tail-only
    float* pbv = slotB + 4096;
    float* pbi = slotB + 68096;
    // h planes live in d_out (dead before final outputs are written)
    bf16* h_hi = (bf16*)d_out;
    bf16* h_lo = h_hi + 8192000;
    float* tokf = (float*)d_out + 8192000;

    const dim3 blk(256);
    const dim3 g512(4, 125), g1024(8, 125), g1536(12, 125);

    embed_kernel<<<dim3(NTOK), dim3(128), 0, stream>>>(noisy, codebook, pos_enc, y);

    for (int l = 0; l < 4; ++l) {
        ln_planes<0><<<dim3(4000), blk, 0, stream>>>(y, h_hi, h_lo, ln1_g + l * E, ln1_b + l * E);
        split_w<<<dim3(3072), blk, 0, stream>>>(qkv_w + (size_t)l * 1536 * E, E, 9, 1536 * E, wA_hi, wA_lo);
        gemm_split<4><<<g1536, blk, 0, stream>>>(
            h_hi, h_lo, E, wA_hi, wA_lo, E, qkv_b + (size_t)l * 1536,
            nullptr, 0, qkvh, qkvl, 1536, nullptr, nullptr, nullptr, nullptr, E);
        vtrans<<<dim3(16, 128), blk, 0, stream>>>(qkvh, qkvl, vth, vtl);  // overwrites wA (dead)
        attn_mfma<<<dim3(16, 128), blk, 0, stream>>>(qkvh, qkvl, vth, vtl, h_hi, h_lo);
        split_w<<<dim3(1024), blk, 0, stream>>>(out_w + (size_t)l * E * E, E, 9, E * E, wB_hi, wB_lo);
        gemm_split<1><<<g512, blk, 0, stream>>>(
            h_hi, h_lo, E, wB_hi, wB_lo, E, out_b + (size_t)l * E,
            y, E, nullptr, nullptr, 0, nullptr, nullptr, nullptr, nullptr, E);
        ln_planes<0><<<dim3(4000), blk, 0, stream>>>(y, h_hi, h_lo, ln2_g + l * E, ln2_b + l * E);
        split_w<<<dim3(4096), blk, 0, stream>>>(ff1_w + (size_t)l * FFD * E, E, 9, FFD * E, wA_hi, wA_lo);
        split_w<<<dim3(4096), blk, 0, stream>>>(ff2_w + (size_t)l * E * FFD, FFD, 11, E * FFD, wB_hi, wB_lo);
        for (int c = 0; c < 2; ++c) {
            gemm_split<2><<<g1024, blk, 0, stream>>>(
                h_hi, h_lo, E, wA_hi + (size_t)c * 1024 * E, wA_lo + (size_t)c * 1024 * E, E,
                ff1_b + (size_t)l * FFD + c * 1024,
                nullptr, 0, mid_hi, mid_lo, 1024, nullptr, nullptr, nullptr, nullptr, E);
            gemm_split<1><<<g512, blk, 0, stream>>>(
                mid_hi, mid_lo, 1024, wB_hi + c * 1024, wB_lo + c * 1024, FFD,
                (c == 0) ? (ff2_b + (size_t)l * E) : nullptr,
                y, E, nullptr, nullptr, 0, nullptr, nullptr, nullptr, nullptr, 1024);
        }
    }

    // tail
    ln_planes<0><<<dim3(4000), blk, 0, stream>>>(y, h_hi, h_lo, fin_g, fin_b);
    split_w<<<dim3(1024), blk, 0, stream>>>(pp1_w, E, 9, E * E, wA_hi, wA_lo);
    gemm_split<0><<<g512, blk, 0, stream>>>(
        h_hi, h_lo, E, wA_hi, wA_lo, E, pp1_b,
        slotB, E, nullptr, nullptr, 0, nullptr, nullptr, nullptr, nullptr, E);
    ln_planes<1><<<dim3(4000), blk, 0, stream>>>(slotB, h_hi, h_lo, pp_ln_g, pp_ln_b);
    split_w<<<dim3(1024), blk, 0, stream>>>(pp2_w, E, 9, E * E, wB_hi, wB_lo);
    gemm_split<3><<<g512, blk, 0, stream>>>(
        h_hi, h_lo, E, wB_hi, wB_lo, E, pp2_b,
        nullptr, 0, e_hi, e_lo, E, noisy, codebook, pos_enc, res_w, E);
    split_w<<<dim3(1024), blk, 0, stream>>>(fc1_w, E, 9, E * E, wA_hi, wA_lo);
    gemm_split<0><<<g512, blk, 0, stream>>>(
        e_hi, e_lo, E, wA_hi, wA_lo, E, fc1_b,
        slotB, E, nullptr, nullptr, 0, nullptr, nullptr, nullptr, nullptr, E);
    ln_planes<1><<<dim3(4000), blk, 0, stream>>>(slotB, h_hi, h_lo, fc_ln_g, fc_ln_b);
    split_w<<<dim3(1024), blk, 0, stream>>>(fc2_w, E, 9, E * E, wB_hi, wB_lo);
    gemm_split<0><<<g512, blk, 0, stream>>>(
        h_hi, h_lo, E, wB_hi, wB_lo, E, fc2_b,
        slotA, E, nullptr, nullptr, 0, nullptr, nullptr, nullptr, nullptr, E);   // fc -> slotA

    cbnorm_kernel<<<dim3(1024), blk, 0, stream>>>(codebook, cbn);
    argmin_kernel<<<dim3(4, 250), blk, 0, stream>>>(slotA, codebook, cbn, pbv, pbi);
    argmin_combine<<<dim3(63), blk, 0, stream>>>(pbv, pbi, tokf);
    hipMemcpyAsync(d_out, slotA, (size_t)8192000 * 4, hipMemcpyDeviceToDevice, stream);
}

// Round 5
// 4233.480 us; speedup vs baseline: 3.3073x; 1.0339x over previous
//
#include <hip/hip_runtime.h>
#include <hip/hip_bf16.h>
#include <math.h>

#define NTOK 16000
#define E    512
#define FFD  2048
#define CBN  4096
#define SEQ  1000
#define NH   8
#define VLD  1008   // Vt padded leading dim (s), multiple of 8

typedef __hip_bfloat16 bf16;
typedef __attribute__((ext_vector_type(8))) short short8;
typedef __attribute__((ext_vector_type(4))) float f32x4;

__device__ __forceinline__ float gelu_f(float v) {
    return 0.5f * v * (1.0f + erff(v * 0.70710678118654752f));
}

__device__ __forceinline__ void split_store(float v, bf16* hi, bf16* lo, size_t idx) {
    bf16 h = __float2bfloat16(v);
    hi[idx] = h;
    lo[idx] = __float2bfloat16(v - __bfloat162float(h));
}

// top-2 insert with np.argmin tiebreak (smaller index wins on equal value)
__device__ __forceinline__ void t2_ins(float v, int c, float& v1, int& c1, float& v2, int& c2) {
    const bool b1 = (v < v1) || (v == v1 && c < c1);
    const bool b2 = (v < v2) || (v == v2 && c < c2);
    if (b1) { v2 = v1; c2 = c1; v1 = v; c1 = c; }
    else if (b2) { v2 = v; c2 = c; }
}

// ---------------------------------------------------------------- embed -> y (fp32)
__global__ __launch_bounds__(128) void embed_kernel(const int* __restrict__ tok,
                                                    const float* __restrict__ cb,
                                                    const float* __restrict__ pe,
                                                    float* __restrict__ y) {
    const int row = blockIdx.x;
    const int s = row % SEQ;
    const int t = tok[row];
    const int c = threadIdx.x * 4;
    const float4 cv = *(const float4*)(cb + (size_t)t * E + c);
    const float4 pv = *(const float4*)(pe + (size_t)s * E + c);
    *(float4*)(y + (size_t)row * E + c) =
        make_float4(cv.x + pv.x, cv.y + pv.y, cv.z + pv.z, cv.w + pv.w);
}

// ---------------------------------------------------------------- weight split fp32 -> hi/lo bf16 (compact dst)
__global__ __launch_bounds__(256) void split_w(const float* __restrict__ src, int ld,
                                               int cols_log2, int n,
                                               bf16* __restrict__ hi, bf16* __restrict__ lo) {
    const int i = blockIdx.x * 256 + threadIdx.x;
    if (i >= n) return;
    const int r = i >> cols_log2;
    const int c = i & ((1 << cols_log2) - 1);
    const float v = src[(size_t)r * ld + c];
    split_store(v, hi, lo, i);
}

// ---------------------------------------------------------------- layernorm -> hi/lo planes (1 wave/row)
template<int GELU>
__global__ __launch_bounds__(256) void ln_planes(const float* __restrict__ in,
                                                 bf16* __restrict__ hi, bf16* __restrict__ lo,
                                                 const float* __restrict__ g,
                                                 const float* __restrict__ b) {
    const int lane = threadIdx.x & 63;
    const int row = blockIdx.x * 4 + (threadIdx.x >> 6);
    const float* p = in + (size_t)row * E;
    const float4 v0 = *(const float4*)(p + lane * 4);
    const float4 v1 = *(const float4*)(p + 256 + lane * 4);
    float sum = v0.x + v0.y + v0.z + v0.w + v1.x + v1.y + v1.z + v1.w;
    float sq = v0.x * v0.x + v0.y * v0.y + v0.z * v0.z + v0.w * v0.w
             + v1.x * v1.x + v1.y * v1.y + v1.z * v1.z + v1.w * v1.w;
#pragma unroll
    for (int m = 1; m < 64; m <<= 1) {
        sum += __shfl_xor(sum, m);
        sq += __shfl_xor(sq, m);
    }
    const float mean = sum * (1.0f / 512.0f);
    const float var = sq * (1.0f / 512.0f) - mean * mean;
    const float rstd = rsqrtf(var + 1e-5f);
    const float4 g0 = *(const float4*)(g + lane * 4);
    const float4 g1 = *(const float4*)(g + 256 + lane * 4);
    const float4 b0 = *(const float4*)(b + lane * 4);
    const float4 b1 = *(const float4*)(b + 256 + lane * 4);
    const size_t base = (size_t)row * E;
    float o;
    const float vv0[4] = {v0.x, v0.y, v0.z, v0.w};
    const float gg0[4] = {g0.x, g0.y, g0.z, g0.w};
    const float bb0[4] = {b0.x, b0.y, b0.z, b0.w};
    const float vv1[4] = {v1.x, v1.y, v1.z, v1.w};
    const float gg1[4] = {g1.x, g1.y, g1.z, g1.w};
    const float bb1[4] = {b1.x, b1.y, b1.z, b1.w};
#pragma unroll
    for (int t = 0; t < 4; ++t) {
        o = (vv0[t] - mean) * rstd * gg0[t] + bb0[t];
        if (GELU) o = gelu_f(o);
        split_store(o, hi, lo, base + lane * 4 + t);
        o = (vv1[t] - mean) * rstd * gg1[t] + bb1[t];
        if (GELU) o = gelu_f(o);
        split_store(o, hi, lo, base + 256 + lane * 4 + t);
    }
}

// ---------------------------------------------------------------- split-bf16 MFMA NT GEMM
// C[M,N] = A[M,:]·W[N,:]^T via AhWh + AhWl + AlWh
// 128x128 tile, BK=32, 256 threads = 4 waves (2x2 of 64x64)
// OUT: 0 = C fp32 (+bias); 1 = C += (+bias); 2 = gelu -> planes;
//      3 = emb(r,c) + resw*(v+bias) -> planes; 4 = plain -> planes
template<int OUT>
__global__ __launch_bounds__(256) void gemm_split(
    const bf16* __restrict__ Ah, const bf16* __restrict__ Al, int lda,
    const bf16* __restrict__ Wh, const bf16* __restrict__ Wl, int ldw,
    const float* __restrict__ bias,
    float* __restrict__ C, int ldc,
    bf16* __restrict__ Ohi, bf16* __restrict__ Olo, int ldp,
    const int* __restrict__ noisy, const float* __restrict__ cb,
    const float* __restrict__ pe, const float* __restrict__ resw,
    int K) {
    __shared__ short Ash[2][128][40];   // [plane][row][k + 8 pad]
    __shared__ short Wsh[2][128][40];
    const int tid = threadIdx.x;
    const int rowBase = blockIdx.y * 128;
    const int colBase = blockIdx.x * 128;
    const int wave = tid >> 6, lane = tid & 63;
    const int wm = (wave & 1) * 64, wn = (wave >> 1) * 64;
    const int lm = lane & 15;
    const int q8 = (lane >> 4) * 8;
    const int r0 = tid >> 2;          // 0..63
    const int kq = (tid & 3) * 8;     // 0,8,16,24

    f32x4 acc[4][4];
#pragma unroll
    for (int i = 0; i < 4; ++i)
#pragma unroll
        for (int j = 0; j < 4; ++j)
            acc[i][j] = (f32x4){0.f, 0.f, 0.f, 0.f};

    for (int k0 = 0; k0 < K; k0 += 32) {
        __syncthreads();
        {
            const size_t a0 = (size_t)(rowBase + r0) * lda + k0 + kq;
            const size_t a1 = (size_t)(rowBase + r0 + 64) * lda + k0 + kq;
            const size_t w0 = (size_t)(colBase + r0) * ldw + k0 + kq;
            const size_t w1 = (size_t)(colBase + r0 + 64) * ldw + k0 + kq;
            *(short8*)&Ash[0][r0][kq]      = *(const short8*)(Ah + a0);
            *(short8*)&Ash[0][r0 + 64][kq] = *(const short8*)(Ah + a1);
            *(short8*)&Ash[1][r0][kq]      = *(const short8*)(Al + a0);
            *(short8*)&Ash[1][r0 + 64][kq] = *(const short8*)(Al + a1);
            *(short8*)&Wsh[0][r0][kq]      = *(const short8*)(Wh + w0);
            *(short8*)&Wsh[0][r0 + 64][kq] = *(const short8*)(Wh + w1);
            *(short8*)&Wsh[1][r0][kq]      = *(const short8*)(Wl + w0);
            *(short8*)&Wsh[1][r0 + 64][kq] = *(const short8*)(Wl + w1);
        }
        __syncthreads();
        short8 ah[4], al[4], wh[4], wl[4];
#pragma unroll
        for (int i = 0; i < 4; ++i) {
            ah[i] = *(const short8*)&Ash[0][wm + i * 16 + lm][q8];
            al[i] = *(const short8*)&Ash[1][wm + i * 16 + lm][q8];
            wh[i] = *(const short8*)&Wsh[0][wn + i * 16 + lm][q8];
            wl[i] = *(const short8*)&Wsh[1][wn + i * 16 + lm][q8];
        }
#pragma unroll
        for (int i = 0; i < 4; ++i)
#pragma unroll
            for (int j = 0; j < 4; ++j)
                acc[i][j] = __builtin_amdgcn_mfma_f32_16x16x32_bf16(ah[i], wh[j], acc[i][j], 0, 0, 0);
#pragma unroll
        for (int i = 0; i < 4; ++i)
#pragma unroll
            for (int j = 0; j < 4; ++j)
                acc[i][j] = __builtin_amdgcn_mfma_f32_16x16x32_bf16(ah[i], wl[j], acc[i][j], 0, 0, 0);
#pragma unroll
        for (int i = 0; i < 4; ++i)
#pragma unroll
            for (int j = 0; j < 4; ++j)
                acc[i][j] = __builtin_amdgcn_mfma_f32_16x16x32_bf16(al[i], wh[j], acc[i][j], 0, 0, 0);
    }

    // epilogue: C/D layout col = lane&15, row = (lane>>4)*4 + reg
    float bv[4];
#pragma unroll
    for (int j = 0; j < 4; ++j)
        bv[j] = bias ? bias[colBase + wn + j * 16 + lm] : 0.f;
    float scv = 0.f;
    if (OUT == 3) scv = resw[0];
#pragma unroll
    for (int i = 0; i < 4; ++i) {
#pragma unroll
        for (int reg = 0; reg < 4; ++reg) {
            const int r = rowBase + wm + i * 16 + (lane >> 4) * 4 + reg;
            int tok = 0, srow = 0;
            if (OUT == 3) { tok = noisy[r]; srow = r % SEQ; }
#pragma unroll
            for (int j = 0; j < 4; ++j) {
                const int col = colBase + wn + j * 16 + lm;
                float v = acc[i][j][reg] + bv[j];
                if (OUT == 0) {
                    C[(size_t)r * ldc + col] = v;
                } else if (OUT == 1) {
                    float* cp = C + (size_t)r * ldc + col;
                    *cp = *cp + v;
                } else if (OUT == 2) {
                    v = gelu_f(v);
                    split_store(v, Ohi, Olo, (size_t)r * ldp + col);
                } else if (OUT == 3) {
                    const float xv = cb[(size_t)tok * E + col] + pe[(size_t)srow * E + col];
                    v = xv + scv * v;
                    split_store(v, Ohi, Olo, (size_t)r * ldp + col);
                } else { // OUT == 4
                    split_store(v, Ohi, Olo, (size_t)r * ldp + col);
                }
            }
        }
    }
}

// ---------------------------------------------------------------- V transpose: qkv planes -> Vt[bh*64+d][s] (ld VLD)
__global__ __launch_bounds__(256) void vtrans(const bf16* __restrict__ vh_src,
                                              const bf16* __restrict__ vl_src,
                                              bf16* __restrict__ vth,
                                              bf16* __restrict__ vtl) {
    __shared__ short T[64][72];
    const int tid = threadIdx.x;
    const int st = blockIdx.x;   // 16 s-tiles of 64
    const int bh = blockIdx.y;   // 128
    const int b = bh >> 3, h = bh & 7;
    const int sr = tid >> 2, dq = (tid & 3) * 16;
    const int s_g = st * 64 + sr;
    const int od = tid >> 3;          // 0..31 (+32)
    const int osq = (tid & 7) * 8;    // 0..56
#pragma unroll
    for (int p = 0; p < 2; ++p) {
        const short* src = (const short*)(p ? vl_src : vh_src);
        short* dst = (short*)(p ? vtl : vth);
        short8 a0 = {0, 0, 0, 0, 0, 0, 0, 0};
        short8 a1 = {0, 0, 0, 0, 0, 0, 0, 0};
        if (s_g < SEQ) {
            const short* sp = src + (size_t)(b * SEQ + s_g) * 1536 + 1024 + h * 64 + dq;
            a0 = *(const short8*)sp;
            a1 = *(const short8*)(sp + 8);
        }
        __syncthreads();
#pragma unroll
        for (int j = 0; j < 8; ++j) T[dq + j][sr] = a0[j];
#pragma unroll
        for (int j = 0; j < 8; ++j) T[dq + 8 + j][sr] = a1[j];
        __syncthreads();
        const int scol = st * 64 + osq;
        if (scol + 8 <= VLD) {
            const short8 o0 = *(const short8*)&T[od][osq];
            const short8 o1 = *(const short8*)&T[od + 32][osq];
            *(short8*)(dst + (size_t)(bh * 64 + od) * VLD + scol) = o0;
            *(short8*)(dst + (size_t)(bh * 64 + od + 32) * VLD + scol) = o1;
        }
    }
}

// ---------------------------------------------------------------- MFMA flash attention (split bf16)
__global__ __launch_bounds__(256) void attn_mfma(const bf16* __restrict__ qkh,
                                                 const bf16* __restrict__ qkl,
                                                 const bf16* __restrict__ vth,
                                                 const bf16* __restrict__ vtl,
                                                 bf16* __restrict__ chi,
                                                 bf16* __restrict__ clo) {
    __shared__ short QPs[2][64][72];   // Q staging, then P
    __shared__ short Ks[2][64][72];
    __shared__ short Vs[2][64][72];    // Vt tile: [d][n]
    const int tid = threadIdx.x;
    const int qt = blockIdx.x, bh = blockIdx.y;
    const int b = bh >> 3, h = bh & 7;
    const int wave = tid >> 6, lane = tid & 63;
    const int lm = lane & 15, g = lane >> 4, q8 = g * 8;
    const int wq = wave * 16;
    const int r0 = tid >> 2, kq = (tid & 3) * 16;

    {
        const int q = qt * 64 + r0;
        short8 z = {0, 0, 0, 0, 0, 0, 0, 0};
        short8 a0 = z, a1 = z, b0 = z, b1 = z;
        if (q < SEQ) {
            const size_t base = (size_t)(b * SEQ + q) * 1536 + h * 64 + kq;
            a0 = *(const short8*)((const short*)qkh + base);
            a1 = *(const short8*)((const short*)qkh + base + 8);
            b0 = *(const short8*)((const short*)qkl + base);
            b1 = *(const short8*)((const short*)qkl + base + 8);
        }
        *(short8*)&QPs[0][r0][kq] = a0; *(short8*)&QPs[0][r0][kq + 8] = a1;
        *(short8*)&QPs[1][r0][kq] = b0; *(short8*)&QPs[1][r0][kq + 8] = b1;
    }
    __syncthreads();
    short8 qfh[2], qfl[2];
#pragma unroll
    for (int t = 0; t < 2; ++t) {
        qfh[t] = *(const short8*)&QPs[0][wq + lm][t * 32 + q8];
        qfl[t] = *(const short8*)&QPs[1][wq + lm][t * 32 + q8];
    }

    float m_i[4] = {-3e38f, -3e38f, -3e38f, -3e38f};
    float l_i[4] = {0.f, 0.f, 0.f, 0.f};
    f32x4 o[4];
#pragma unroll
    for (int dt = 0; dt < 4; ++dt) o[dt] = (f32x4){0.f, 0.f, 0.f, 0.f};

    for (int kb = 0; kb < SEQ; kb += 64) {
        __syncthreads();
        {
            const int kr = kb + r0;
            short8 z = {0, 0, 0, 0, 0, 0, 0, 0};
            short8 a0 = z, a1 = z, b0 = z, b1 = z;
            if (kr < SEQ) {
                const size_t base = (size_t)(b * SEQ + kr) * 1536 + 512 + h * 64 + kq;
                a0 = *(const short8*)((const short*)qkh + base);
                a1 = *(const short8*)((const short*)qkh + base + 8);
                b0 = *(const short8*)((const short*)qkl + base);
                b1 = *(const short8*)((const short*)qkl + base + 8);
            }
            *(short8*)&Ks[0][r0][kq] = a0; *(short8*)&Ks[0][r0][kq + 8] = a1;
            *(short8*)&Ks[1][r0][kq] = b0; *(short8*)&Ks[1][r0][kq + 8] = b1;
            const size_t vbase = (size_t)(bh * 64 + r0) * VLD + kb + kq;
            short8 v0 = z, v1 = z, w0 = z, w1 = z;
            if (kb + kq + 8 <= VLD) {
                v0 = *(const short8*)((const short*)vth + vbase);
                w0 = *(const short8*)((const short*)vtl + vbase);
            }
            if (kb + kq + 16 <= VLD) {
                v1 = *(const short8*)((const short*)vth + vbase + 8);
                w1 = *(const short8*)((const short*)vtl + vbase + 8);
            }
            *(short8*)&Vs[0][r0][kq] = v0; *(short8*)&Vs[0][r0][kq + 8] = v1;
            *(short8*)&Vs[1][r0][kq] = w0; *(short8*)&Vs[1][r0][kq + 8] = w1;
        }
        __syncthreads();
        f32x4 sac[4];
#pragma unroll
        for (int j = 0; j < 4; ++j) sac[j] = (f32x4){0.f, 0.f, 0.f, 0.f};
#pragma unroll
        for (int t = 0; t < 2; ++t) {
#pragma unroll
            for (int j = 0; j < 4; ++j) {
                const short8 kh = *(const short8*)&Ks[0][j * 16 + lm][t * 32 + q8];
                const short8 kl = *(const short8*)&Ks[1][j * 16 + lm][t * 32 + q8];
                sac[j] = __builtin_amdgcn_mfma_f32_16x16x32_bf16(qfh[t], kh, sac[j], 0, 0, 0);
                sac[j] = __builtin_amdgcn_mfma_f32_16x16x32_bf16(qfh[t], kl, sac[j], 0, 0, 0);
                sac[j] = __builtin_amdgcn_mfma_f32_16x16x32_bf16(qfl[t], kh, sac[j], 0, 0, 0);
            }
        }
        float alpha_v[4];
#pragma unroll
        for (int reg = 0; reg < 4; ++reg) {
            float sv[4];
            float rm = -3e38f;
#pragma unroll
            for (int j = 0; j < 4; ++j) {
                const int kc = kb + j * 16 + lm;
                float s = sac[j][reg] * 0.125f;
                s = (kc < SEQ) ? s : -3e38f;
                sv[j] = s;
                rm = fmaxf(rm, s);
            }
#pragma unroll
            for (int m = 1; m < 16; m <<= 1) rm = fmaxf(rm, __shfl_xor(rm, m));
            const float mn = fmaxf(m_i[reg], rm);
            const float al = expf(m_i[reg] - mn);
            float rs = 0.f;
            const int prow = wq + g * 4 + reg;
#pragma unroll
            for (int j = 0; j < 4; ++j) {
                const float pv = expf(sv[j] - mn);
                rs += pv;
                bf16 phb = __float2bfloat16(pv);
                bf16 plb = __float2bfloat16(pv - __bfloat162float(phb));
                QPs[0][prow][j * 16 + lm] = *reinterpret_cast<short*>(&phb);
                QPs[1][prow][j * 16 + lm] = *reinterpret_cast<short*>(&plb);
            }
#pragma unroll
            for (int m = 1; m < 16; m <<= 1) rs += __shfl_xor(rs, m);
            l_i[reg] = l_i[reg] * al + rs;
            m_i[reg] = mn;
            alpha_v[reg] = al;
        }
        const f32x4 av = {alpha_v[0], alpha_v[1], alpha_v[2], alpha_v[3]};
#pragma unroll
        for (int dt = 0; dt < 4; ++dt) o[dt] *= av;
        __syncthreads();
#pragma unroll
        for (int t = 0; t < 2; ++t) {
            const short8 ph = *(const short8*)&QPs[0][wq + lm][t * 32 + q8];
            const short8 pl = *(const short8*)&QPs[1][wq + lm][t * 32 + q8];
#pragma unroll
            for (int dt = 0; dt < 4; ++dt) {
                const short8 vh = *(const short8*)&Vs[0][dt * 16 + lm][t * 32 + q8];
                const short8 vl = *(const short8*)&Vs[1][dt * 16 + lm][t * 32 + q8];
                o[dt] = __builtin_amdgcn_mfma_f32_16x16x32_bf16(ph, vh, o[dt], 0, 0, 0);
                o[dt] = __builtin_amdgcn_mfma_f32_16x16x32_bf16(ph, vl, o[dt], 0, 0, 0);
                o[dt] = __builtin_amdgcn_mfma_f32_16x16x32_bf16(pl, vh, o[dt], 0, 0, 0);
            }
        }
    }
#pragma unroll
    for (int reg = 0; reg < 4; ++reg) {
        const int q = qt * 64 + wq + g * 4 + reg;
        if (q < SEQ) {
            const float inv = 1.0f / l_i[reg];
#pragma unroll
            for (int dt = 0; dt < 4; ++dt) {
                const size_t idx = (size_t)(b * SEQ + q) * E + h * 64 + dt * 16 + lm;
                split_store(o[dt][reg] * inv, chi, clo, idx);
            }
        }
    }
}

// ---------------------------------------------------------------- codebook row norms
__global__ __launch_bounds__(256) void cbnorm_kernel(const float* __restrict__ cb,
                                                     float* __restrict__ out) {
    const int lane = threadIdx.x & 63;
    const int row = blockIdx.x * 4 + (threadIdx.x >> 6);
    const float* p = cb + (size_t)row * E;
    const float4 v0 = *(const float4*)(p + lane * 4);
    const float4 v1 = *(const float4*)(p + 256 + lane * 4);
    float sq = v0.x * v0.x + v0.y * v0.y + v0.z * v0.z + v0.w * v0.w
             + v1.x * v1.x + v1.y * v1.y + v1.z * v1.z + v1.w * v1.w;
#pragma unroll
    for (int m = 1; m < 64; m <<= 1) sq += __shfl_xor(sq, m);
    if (lane == 0) out[row] = sq;
}

// ---------------------------------------------------------------- stage A: split-bf16 MFMA distance, per-row top2 partials
// grid (32 col-blocks, 125 row-blocks); part[row*64 + bx*2 + half] = (v1, idx1, v2, idx2)
__global__ __launch_bounds__(256) void argmin_mfma(
    const bf16* __restrict__ Ah, const bf16* __restrict__ Al,
    const bf16* __restrict__ Wh, const bf16* __restrict__ Wl,
    const float* __restrict__ cbn, float4* __restrict__ part) {
    __shared__ short Ash[2][128][40];
    __shared__ short Wsh[2][128][40];
    const int tid = threadIdx.x;
    const int rowBase = blockIdx.y * 128;
    const int colBase = blockIdx.x * 128;
    const int wave = tid >> 6, lane = tid & 63;
    const int wm = (wave & 1) * 64, wn = (wave >> 1) * 64;
    const int lm = lane & 15;
    const int q8 = (lane >> 4) * 8;
    const int r0 = tid >> 2;
    const int kq = (tid & 3) * 8;

    f32x4 acc[4][4];
#pragma unroll
    for (int i = 0; i < 4; ++i)
#pragma unroll
        for (int j = 0; j < 4; ++j)
            acc[i][j] = (f32x4){0.f, 0.f, 0.f, 0.f};

    for (int k0 = 0; k0 < E; k0 += 32) {
        __syncthreads();
        {
            const size_t a0 = (size_t)(rowBase + r0) * E + k0 + kq;
            const size_t a1 = (size_t)(rowBase + r0 + 64) * E + k0 + kq;
            const size_t w0 = (size_t)(colBase + r0) * E + k0 + kq;
            const size_t w1 = (size_t)(colBase + r0 + 64) * E + k0 + kq;
            *(short8*)&Ash[0][r0][kq]      = *(const short8*)(Ah + a0);
            *(short8*)&Ash[0][r0 + 64][kq] = *(const short8*)(Ah + a1);
            *(short8*)&Ash[1][r0][kq]      = *(const short8*)(Al + a0);
            *(short8*)&Ash[1][r0 + 64][kq] = *(const short8*)(Al + a1);
            *(short8*)&Wsh[0][r0][kq]      = *(const short8*)(Wh + w0);
            *(short8*)&Wsh[0][r0 + 64][kq] = *(const short8*)(Wh + w1);
            *(short8*)&Wsh[1][r0][kq]      = *(const short8*)(Wl + w0);
            *(short8*)&Wsh[1][r0 + 64][kq] = *(const short8*)(Wl + w1);
        }
        __syncthreads();
        short8 ah[4], al[4], wh[4], wl[4];
#pragma unroll
        for (int i = 0; i < 4; ++i) {
            ah[i] = *(const short8*)&Ash[0][wm + i * 16 + lm][q8];
            al[i] = *(const short8*)&Ash[1][wm + i * 16 + lm][q8];
            wh[i] = *(const short8*)&Wsh[0][wn + i * 16 + lm][q8];
            wl[i] = *(const short8*)&Wsh[1][wn + i * 16 + lm][q8];
        }
#pragma unroll
        for (int i = 0; i < 4; ++i)
#pragma unroll
            for (int j = 0; j < 4; ++j)
                acc[i][j] = __builtin_amdgcn_mfma_f32_16x16x32_bf16(ah[i], wh[j], acc[i][j], 0, 0, 0);
#pragma unroll
        for (int i = 0; i < 4; ++i)
#pragma unroll
            for (int j = 0; j < 4; ++j)
                acc[i][j] = __builtin_amdgcn_mfma_f32_16x16x32_bf16(ah[i], wl[j], acc[i][j], 0, 0, 0);
#pragma unroll
        for (int i = 0; i < 4; ++i)
#pragma unroll
            for (int j = 0; j < 4; ++j)
                acc[i][j] = __builtin_amdgcn_mfma_f32_16x16x32_bf16(al[i], wh[j], acc[i][j], 0, 0, 0);
    }

    // per-row top2 over this 64-col half, then cross-lane (lm group) reduce
    float nv[4];
#pragma unroll
    for (int j = 0; j < 4; ++j) nv[j] = cbn[colBase + wn + j * 16 + lm];
    const int hx = blockIdx.x * 2 + (wn >> 6);
#pragma unroll
    for (int i = 0; i < 4; ++i) {
#pragma unroll
        for (int reg = 0; reg < 4; ++reg) {
            const int r = rowBase + wm + i * 16 + (lane >> 4) * 4 + reg;
            float v1 = 3e38f, v2 = 3e38f;
            int c1 = 0x7fffffff, c2 = 0x7fffffff;
#pragma unroll
            for (int j = 0; j < 4; ++j) {
                const int col = colBase + wn + j * 16 + lm;
                const float d = nv[j] - 2.0f * acc[i][j][reg];
                t2_ins(d, col, v1, c1, v2, c2);
            }
#pragma unroll
            for (int m = 1; m < 16; m <<= 1) {
                const float w1 = __shfl_xor(v1, m); const int d1 = __shfl_xor(c1, m);
                const float w2 = __shfl_xor(v2, m); const int d2 = __shfl_xor(c2, m);
                t2_ins(w1, d1, v1, c1, v2, c2);
                t2_ins(w2, d2, v1, c1, v2, c2);
            }
            if (lm == 0)
                part[(size_t)r * 64 + hx] = make_float4(v1, (float)c1, v2, (float)c2);
        }
    }
}

// ---------------------------------------------------------------- stage B: merge partials, exact fp32 rescore of top2
__global__ __launch_bounds__(256) void argmin_exact(const float4* __restrict__ part,
                                                    const float* __restrict__ fc,
                                                    const float* __restrict__ cb,
                                                    const float* __restrict__ cbn,
                                                    float* __restrict__ tokf) {
    const int wave = threadIdx.x >> 6, lane = threadIdx.x & 63;
    const int r = blockIdx.x * 4 + wave;   // 4000 blocks
    const float4 p = part[(size_t)r * 64 + lane];
    float v1 = p.x, v2 = p.z;
    int c1 = (int)p.y, c2 = (int)p.w;
#pragma unroll
    for (int m = 1; m < 64; m <<= 1) {
        const float w1 = __shfl_xor(v1, m); const int d1 = __shfl_xor(c1, m);
        const float w2 = __shfl_xor(v2, m); const int d2 = __shfl_xor(c2, m);
        t2_ins(w1, d1, v1, c1, v2, c2);
        t2_ins(w2, d2, v1, c1, v2, c2);
    }
    // exact fp32 d2 for c1, c2
    const float* fr = fc + (size_t)r * E + lane * 8;
    const float* p1 = cb + (size_t)c1 * E + lane * 8;
    const float* p2 = cb + (size_t)c2 * E + lane * 8;
    float d1 = 0.f, d2 = 0.f;
#pragma unroll
    for (int j = 0; j < 8; ++j) {
        const float f = fr[j];
        d1 += f * p1[j];
        d2 += f * p2[j];
    }
#pragma unroll
    for (int m = 1; m < 64; m <<= 1) {
        d1 += __shfl_xor(d1, m);
        d2 += __shfl_xor(d2, m);
    }
    d1 = cbn[c1] - 2.0f * d1;
    d2 = cbn[c2] - 2.0f * d2;
    const int win = ((d1 < d2) || (d1 == d2 && c1 < c2)) ? c1 : c2;
    if (lane == 0) tokf[r] = (float)win;
}

// ---------------------------------------------------------------- launch
extern "C" void kernel_launch(void* const* d_in, const int* in_sizes, int n_in,
                              void* d_out, int out_size, void* d_ws, size_t ws_size,
                              hipStream_t stream) {
    const int* noisy = (const int*)d_in[0];
    const float* codebook = (const float*)d_in[1];
    const float* pos_enc = (const float*)d_in[2];
    const float* qkv_w = (const float*)d_in[3];
    const float* qkv_b = (const float*)d_in[4];
    const float* out_w = (const float*)d_in[5];
    const float* out_b = (const float*)d_in[6];
    const float* ln1_g = (const float*)d_in[7];
    const float* ln1_b = (const float*)d_in[8];
    const float* ln2_g = (const float*)d_in[9];
    const float* ln2_b = (const float*)d_in[10];
    const float* ff1_w = (const float*)d_in[11];
    const float* ff1_b = (const float*)d_in[12];
    const float* ff2_w = (const float*)d_in[13];
    const float* ff2_b = (const float*)d_in[14];
    const float* fin_g = (const float*)d_in[15];
    const float* fin_b = (const float*)d_in[16];
    const float* pp1_w = (const float*)d_in[17];
    const float* pp1_b = (const float*)d_in[18];
    const float* pp_ln_g = (const float*)d_in[19];
    const float* pp_ln_b = (const float*)d_in[20];
    const float* pp2_w = (const float*)d_in[21];
    const float* pp2_b = (const float*)d_in[22];
    const float* res_w = (const float*)d_in[23];
    const float* fc1_w = (const float*)d_in[24];
    const float* fc1_b = (const float*)d_in[25];
    const float* fc_ln_g = (const float*)d_in[26];
    const float* fc_ln_b = (const float*)d_in[27];
    const float* fc2_w = (const float*)d_in[28];
    const float* fc2_b = (const float*)d_in[29];

    // workspace (floats), total 41,025,536 floats = 164.1 MB
    float* ws = (float*)d_ws;
    float* y = ws;                        // [0, 8.192M)
    float* REG = ws + 8192000;            // [8.192M, 32.768M)
    bf16* qkvh = (bf16*)REG;              // 16000x1536 shorts
    bf16* qkvl = qkvh + 24576000;
    bf16* mid_hi = (bf16*)REG;            // FF phase: 16000x1024
    bf16* mid_lo = mid_hi + 16384000;
    float* slotA = REG;                   // tail: e planes / fc fp32
    float* slotB = REG + 8192000;         // tail: pp1/fc1 fp32 tmp, then cbn+partials
    bf16* e_hi = (bf16*)slotA;
    bf16* e_lo = e_hi + 8192000;
    float* WV = ws + 32768000;            // [32.768M, 41.0255M): Vt planes OR weight splits OR cb planes
    bf16* vth = (bf16*)WV;                // 8192 x VLD
    bf16* vtl = vth + 8192 * VLD;
    bf16* wA_hi = (bf16*)WV;              // cap 2048x512 each
    bf16* wA_lo = wA_hi + 1048576;
    bf16* wB_hi = wA_lo + 1048576;
    bf16* wB_lo = wB_hi + 1048576;
    bf16* cbh = wB_lo + 1048576;          // 4096x512, after weights (tail only)
    bf16* cbl = cbh + 2097152;
    float* cbn = slotB;                   // tail-only
    float4* part = (float4*)(slotB + 4096);  // 16000 x 64 float4 = 4.096M floats
    // h planes live in d_out (dead before final outputs are written)
    bf16* h_hi = (bf16*)d_out;
    bf16* h_lo = h_hi + 8192000;
    bf16* fcp_hi = (bf16*)d_out;          // fc planes overwrite h planes at the very end
    bf16* fcp_lo = fcp_hi + 8192000;
    float* tokf = (float*)d_out + 8192000;

    const dim3 blk(256);
    const dim3 g512(4, 125), g1024(8, 125), g1536(12, 125);

    embed_kernel<<<dim3(NTOK), dim3(128), 0, stream>>>(noisy, codebook, pos_enc, y);

    for (int l = 0; l < 4; ++l) {
        ln_planes<0><<<dim3(4000), blk, 0, stream>>>(y, h_hi, h_lo, ln1_g + l * E, ln1_b + l * E);
        split_w<<<dim3(3072), blk, 0, stream>>>(qkv_w + (size_t)l * 1536 * E, E, 9, 1536 * E, wA_hi, wA_lo);
        gemm_split<4><<<g1536, blk, 0, stream>>>(
            h_hi, h_lo, E, wA_hi, wA_lo, E, qkv_b + (size_t)l * 1536,
            nullptr, 0, qkvh, qkvl, 1536, nullptr, nullptr, nullptr, nullptr, E);
        vtrans<<<dim3(16, 128), blk, 0, stream>>>(qkvh, qkvl, vth, vtl);  // overwrites wA (dead)
        attn_mfma<<<dim3(16, 128), blk, 0, stream>>>(qkvh, qkvl, vth, vtl, h_hi, h_lo);
        split_w<<<dim3(1024), blk, 0, stream>>>(out_w + (size_t)l * E * E, E, 9, E * E, wB_hi, wB_lo);
        gemm_split<1><<<g512, blk, 0, stream>>>(
            h_hi, h_lo, E, wB_hi, wB_lo, E, out_b + (size_t)l * E,
            y, E, nullptr, nullptr, 0, nullptr, nullptr, nullptr, nullptr, E);
        ln_planes<0><<<dim3(4000), blk, 0, stream>>>(y, h_hi, h_lo, ln2_g + l * E, ln2_b + l * E);
        split_w<<<dim3(4096), blk, 0, stream>>>(ff1_w + (size_t)l * FFD * E, E, 9, FFD * E, wA_hi, wA_lo);
        split_w<<<dim3(4096), blk, 0, stream>>>(ff2_w + (size_t)l * E * FFD, FFD, 11, E * FFD, wB_hi, wB_lo);
        for (int c = 0; c < 2; ++c) {
            gemm_split<2><<<g1024, blk, 0, stream>>>(
                h_hi, h_lo, E, wA_hi + (size_t)c * 1024 * E, wA_lo + (size_t)c * 1024 * E, E,
                ff1_b + (size_t)l * FFD + c * 1024,
                nullptr, 0, mid_hi, mid_lo, 1024, nullptr, nullptr, nullptr, nullptr, E);
            gemm_split<1><<<g512, blk, 0, stream>>>(
                mid_hi, mid_lo, 1024, wB_hi + c * 1024, wB_lo + c * 1024, FFD,
                (c == 0) ? (ff2_b + (size_t)l * E) : nullptr,
                y, E, nullptr, nullptr, 0, nullptr, nullptr, nullptr, nullptr, 1024);
        }
    }

    // tail
    ln_planes<0><<<dim3(4000), blk, 0, stream>>>(y, h_hi, h_lo, fin_g, fin_b);
    split_w<<<dim3(1024), blk, 0, stream>>>(pp1_w, E, 9, E * E, wA_hi, wA_lo);
    gemm_split<0><<<g512, blk, 0, stream>>>(
        h_hi, h_lo, E, wA_hi, wA_lo, E, pp1_b,
        slotB, E, nullptr, nullptr, 0, nullptr, nullptr, nullptr, nullptr, E);
    ln_planes<1><<<dim3(4000), blk, 0, stream>>>(slotB, h_hi, h_lo, pp_ln_g, pp_ln_b);
    split_w<<<dim3(1024), blk, 0, stream>>>(pp2_w, E, 9, E * E, wB_hi, wB_lo);
    gemm_split<3><<<g512, blk, 0, stream>>>(
        h_hi, h_lo, E, wB_hi, wB_lo, E, pp2_b,
        nullptr, 0, e_hi, e_lo, E, noisy, codebook, pos_enc, res_w, E);
    split_w<<<dim3(1024), blk, 0, stream>>>(fc1_w, E, 9, E * E, wA_hi, wA_lo);
    gemm_split<0><<<g512, blk, 0, stream>>>(
        e_hi, e_lo, E, wA_hi, wA_lo, E, fc1_b,
        slotB, E, nullptr, nullptr, 0, nullptr, nullptr, nullptr, nullptr, E);
    ln_planes<1><<<dim3(4000), blk, 0, stream>>>(slotB, h_hi, h_lo, fc_ln_g, fc_ln_b);
    split_w<<<dim3(1024), blk, 0, stream>>>(fc2_w, E, 9, E * E, wB_hi, wB_lo);
    gemm_split<0><<<g512, blk, 0, stream>>>(
        h_hi, h_lo, E, wB_hi, wB_lo, E, fc2_b,
        slotA, E, nullptr, nullptr, 0, nullptr, nullptr, nullptr, nullptr, E);   // fc fp32 -> slotA

    // argmin: approx MFMA top2 + exact fp32 rescore
    split_w<<<dim3(32000), blk, 0, stream>>>(slotA, E, 9, NTOK * E, fcp_hi, fcp_lo);  // fc planes (h dead)
    split_w<<<dim3(8192), blk, 0, stream>>>(codebook, E, 9, CBN * E, cbh, cbl);
    cbnorm_kernel<<<dim3(1024), blk, 0, stream>>>(codebook, cbn);
    argmin_mfma<<<dim3(32, 125), blk, 0, stream>>>(fcp_hi, fcp_lo, cbh, cbl, cbn, part);
    argmin_exact<<<dim3(4000), blk, 0, stream>>>(part, slotA, codebook, cbn, tokf);
    hipMemcpyAsync(d_out, slotA, (size_t)8192000 * 4, hipMemcpyDeviceToDevice, stream);
}

// Round 6
// 3819.055 us; speedup vs baseline: 3.6662x; 1.1085x over previous
//
#include <hip/hip_runtime.h>
#include <hip/hip_bf16.h>
#include <math.h>

#define NTOK 16000
#define E    512
#define FFD  2048
#define CBN  4096
#define SEQ  1000
#define NH   8
#define VLD  1008   // Vt padded leading dim (s), multiple of 8

typedef __hip_bfloat16 bf16;
typedef __attribute__((ext_vector_type(8))) short short8;
typedef __attribute__((ext_vector_type(4))) float f32x4;

__device__ __forceinline__ float gelu_f(float v) {
    return 0.5f * v * (1.0f + erff(v * 0.70710678118654752f));
}

__device__ __forceinline__ void split_store(float v, bf16* hi, bf16* lo, size_t idx) {
    bf16 h = __float2bfloat16(v);
    hi[idx] = h;
    lo[idx] = __float2bfloat16(v - __bfloat162float(h));
}

// top-2 insert with np.argmin tiebreak (smaller index wins on equal value)
__device__ __forceinline__ void t2_ins(float v, int c, float& v1, int& c1, float& v2, int& c2) {
    const bool b1 = (v < v1) || (v == v1 && c < c1);
    const bool b2 = (v < v2) || (v == v2 && c < c2);
    if (b1) { v2 = v1; c2 = c1; v1 = v; c1 = c; }
    else if (b2) { v2 = v; c2 = c; }
}

// ---------------------------------------------------------------- embed -> y (fp32)
__global__ __launch_bounds__(128) void embed_kernel(const int* __restrict__ tok,
                                                    const float* __restrict__ cb,
                                                    const float* __restrict__ pe,
                                                    float* __restrict__ y) {
    const int row = blockIdx.x;
    const int s = row % SEQ;
    const int t = tok[row];
    const int c = threadIdx.x * 4;
    const float4 cv = *(const float4*)(cb + (size_t)t * E + c);
    const float4 pv = *(const float4*)(pe + (size_t)s * E + c);
    *(float4*)(y + (size_t)row * E + c) =
        make_float4(cv.x + pv.x, cv.y + pv.y, cv.z + pv.z, cv.w + pv.w);
}

// ---------------------------------------------------------------- weight split fp32 -> hi/lo bf16 (compact dst)
__global__ __launch_bounds__(256) void split_w(const float* __restrict__ src, int ld,
                                               int cols_log2, int n,
                                               bf16* __restrict__ hi, bf16* __restrict__ lo) {
    const int i = blockIdx.x * 256 + threadIdx.x;
    if (i >= n) return;
    const int r = i >> cols_log2;
    const int c = i & ((1 << cols_log2) - 1);
    const float v = src[(size_t)r * ld + c];
    split_store(v, hi, lo, i);
}

// ---------------------------------------------------------------- layernorm -> hi/lo planes (1 wave/row)
template<int GELU>
__global__ __launch_bounds__(256) void ln_planes(const float* __restrict__ in,
                                                 bf16* __restrict__ hi, bf16* __restrict__ lo,
                                                 const float* __restrict__ g,
                                                 const float* __restrict__ b) {
    const int lane = threadIdx.x & 63;
    const int row = blockIdx.x * 4 + (threadIdx.x >> 6);
    const float* p = in + (size_t)row * E;
    const float4 v0 = *(const float4*)(p + lane * 4);
    const float4 v1 = *(const float4*)(p + 256 + lane * 4);
    float sum = v0.x + v0.y + v0.z + v0.w + v1.x + v1.y + v1.z + v1.w;
    float sq = v0.x * v0.x + v0.y * v0.y + v0.z * v0.z + v0.w * v0.w
             + v1.x * v1.x + v1.y * v1.y + v1.z * v1.z + v1.w * v1.w;
#pragma unroll
    for (int m = 1; m < 64; m <<= 1) {
        sum += __shfl_xor(sum, m);
        sq += __shfl_xor(sq, m);
    }
    const float mean = sum * (1.0f / 512.0f);
    const float var = sq * (1.0f / 512.0f) - mean * mean;
    const float rstd = rsqrtf(var + 1e-5f);
    const float4 g0 = *(const float4*)(g + lane * 4);
    const float4 g1 = *(const float4*)(g + 256 + lane * 4);
    const float4 b0 = *(const float4*)(b + lane * 4);
    const float4 b1 = *(const float4*)(b + 256 + lane * 4);
    const size_t base = (size_t)row * E;
    float o;
    const float vv0[4] = {v0.x, v0.y, v0.z, v0.w};
    const float gg0[4] = {g0.x, g0.y, g0.z, g0.w};
    const float bb0[4] = {b0.x, b0.y, b0.z, b0.w};
    const float vv1[4] = {v1.x, v1.y, v1.z, v1.w};
    const float gg1[4] = {g1.x, g1.y, g1.z, g1.w};
    const float bb1[4] = {b1.x, b1.y, b1.z, b1.w};
#pragma unroll
    for (int t = 0; t < 4; ++t) {
        o = (vv0[t] - mean) * rstd * gg0[t] + bb0[t];
        if (GELU) o = gelu_f(o);
        split_store(o, hi, lo, base + lane * 4 + t);
        o = (vv1[t] - mean) * rstd * gg1[t] + bb1[t];
        if (GELU) o = gelu_f(o);
        split_store(o, hi, lo, base + 256 + lane * 4 + t);
    }
}

// ---------------------------------------------------------------- split-bf16 MFMA NT GEMM
// C[M,N] = A[M,:]·W[N,:]^T via AhWh + AhWl + AlWh
// 128x128 tile, BK=32, 256 threads = 4 waves (2x2 of 64x64)
// OUT: 0 = C fp32 (+bias); 1 = C += (+bias); 2 = gelu -> planes;
//      3 = emb(r,c) + resw*(v+bias) -> planes; 4 = plain -> planes
template<int OUT>
__global__ __launch_bounds__(256) void gemm_split(
    const bf16* __restrict__ Ah, const bf16* __restrict__ Al, int lda,
    const bf16* __restrict__ Wh, const bf16* __restrict__ Wl, int ldw,
    const float* __restrict__ bias,
    float* __restrict__ C, int ldc,
    bf16* __restrict__ Ohi, bf16* __restrict__ Olo, int ldp,
    const int* __restrict__ noisy, const float* __restrict__ cb,
    const float* __restrict__ pe, const float* __restrict__ resw,
    int K) {
    __shared__ short Ash[2][128][40];   // [plane][row][k + 8 pad]
    __shared__ short Wsh[2][128][40];
    const int tid = threadIdx.x;
    const int rowBase = blockIdx.y * 128;
    const int colBase = blockIdx.x * 128;
    const int wave = tid >> 6, lane = tid & 63;
    const int wm = (wave & 1) * 64, wn = (wave >> 1) * 64;
    const int lm = lane & 15;
    const int q8 = (lane >> 4) * 8;
    const int r0 = tid >> 2;          // 0..63
    const int kq = (tid & 3) * 8;     // 0,8,16,24

    f32x4 acc[4][4];
#pragma unroll
    for (int i = 0; i < 4; ++i)
#pragma unroll
        for (int j = 0; j < 4; ++j)
            acc[i][j] = (f32x4){0.f, 0.f, 0.f, 0.f};

    for (int k0 = 0; k0 < K; k0 += 32) {
        __syncthreads();
        {
            const size_t a0 = (size_t)(rowBase + r0) * lda + k0 + kq;
            const size_t a1 = (size_t)(rowBase + r0 + 64) * lda + k0 + kq;
            const size_t w0 = (size_t)(colBase + r0) * ldw + k0 + kq;
            const size_t w1 = (size_t)(colBase + r0 + 64) * ldw + k0 + kq;
            *(short8*)&Ash[0][r0][kq]      = *(const short8*)(Ah + a0);
            *(short8*)&Ash[0][r0 + 64][kq] = *(const short8*)(Ah + a1);
            *(short8*)&Ash[1][r0][kq]      = *(const short8*)(Al + a0);
            *(short8*)&Ash[1][r0 + 64][kq] = *(const short8*)(Al + a1);
            *(short8*)&Wsh[0][r0][kq]      = *(const short8*)(Wh + w0);
            *(short8*)&Wsh[0][r0 + 64][kq] = *(const short8*)(Wh + w1);
            *(short8*)&Wsh[1][r0][kq]      = *(const short8*)(Wl + w0);
            *(short8*)&Wsh[1][r0 + 64][kq] = *(const short8*)(Wl + w1);
        }
        __syncthreads();
        short8 ah[4], al[4], wh[4], wl[4];
#pragma unroll
        for (int i = 0; i < 4; ++i) {
            ah[i] = *(const short8*)&Ash[0][wm + i * 16 + lm][q8];
            al[i] = *(const short8*)&Ash[1][wm + i * 16 + lm][q8];
            wh[i] = *(const short8*)&Wsh[0][wn + i * 16 + lm][q8];
            wl[i] = *(const short8*)&Wsh[1][wn + i * 16 + lm][q8];
        }
#pragma unroll
        for (int i = 0; i < 4; ++i)
#pragma unroll
            for (int j = 0; j < 4; ++j)
                acc[i][j] = __builtin_amdgcn_mfma_f32_16x16x32_bf16(ah[i], wh[j], acc[i][j], 0, 0, 0);
#pragma unroll
        for (int i = 0; i < 4; ++i)
#pragma unroll
            for (int j = 0; j < 4; ++j)
                acc[i][j] = __builtin_amdgcn_mfma_f32_16x16x32_bf16(ah[i], wl[j], acc[i][j], 0, 0, 0);
#pragma unroll
        for (int i = 0; i < 4; ++i)
#pragma unroll
            for (int j = 0; j < 4; ++j)
                acc[i][j] = __builtin_amdgcn_mfma_f32_16x16x32_bf16(al[i], wh[j], acc[i][j], 0, 0, 0);
    }

    // epilogue: C/D layout col = lane&15, row = (lane>>4)*4 + reg
    float bv[4];
#pragma unroll
    for (int j = 0; j < 4; ++j)
        bv[j] = bias ? bias[colBase + wn + j * 16 + lm] : 0.f;
    float scv = 0.f;
    if (OUT == 3) scv = resw[0];
#pragma unroll
    for (int i = 0; i < 4; ++i) {
#pragma unroll
        for (int reg = 0; reg < 4; ++reg) {
            const int r = rowBase + wm + i * 16 + (lane >> 4) * 4 + reg;
            int tok = 0, srow = 0;
            if (OUT == 3) { tok = noisy[r]; srow = r % SEQ; }
#pragma unroll
            for (int j = 0; j < 4; ++j) {
                const int col = colBase + wn + j * 16 + lm;
                float v = acc[i][j][reg] + bv[j];
                if (OUT == 0) {
                    C[(size_t)r * ldc + col] = v;
                } else if (OUT == 1) {
                    float* cp = C + (size_t)r * ldc + col;
                    *cp = *cp + v;
                } else if (OUT == 2) {
                    v = gelu_f(v);
                    split_store(v, Ohi, Olo, (size_t)r * ldp + col);
                } else if (OUT == 3) {
                    const float xv = cb[(size_t)tok * E + col] + pe[(size_t)srow * E + col];
                    v = xv + scv * v;
                    split_store(v, Ohi, Olo, (size_t)r * ldp + col);
                } else { // OUT == 4
                    split_store(v, Ohi, Olo, (size_t)r * ldp + col);
                }
            }
        }
    }
}

// ---------------------------------------------------------------- V transpose: qkv planes -> Vt[bh*64+d][s] (ld VLD)
__global__ __launch_bounds__(256) void vtrans(const bf16* __restrict__ vh_src,
                                              const bf16* __restrict__ vl_src,
                                              bf16* __restrict__ vth,
                                              bf16* __restrict__ vtl) {
    __shared__ short T[64][72];
    const int tid = threadIdx.x;
    const int st = blockIdx.x;   // 16 s-tiles of 64
    const int bh = blockIdx.y;   // 128
    const int b = bh >> 3, h = bh & 7;
    const int sr = tid >> 2, dq = (tid & 3) * 16;
    const int s_g = st * 64 + sr;
    const int od = tid >> 3;          // 0..31 (+32)
    const int osq = (tid & 7) * 8;    // 0..56
#pragma unroll
    for (int p = 0; p < 2; ++p) {
        const short* src = (const short*)(p ? vl_src : vh_src);
        short* dst = (short*)(p ? vtl : vth);
        short8 a0 = {0, 0, 0, 0, 0, 0, 0, 0};
        short8 a1 = {0, 0, 0, 0, 0, 0, 0, 0};
        if (s_g < SEQ) {
            const short* sp = src + (size_t)(b * SEQ + s_g) * 1536 + 1024 + h * 64 + dq;
            a0 = *(const short8*)sp;
            a1 = *(const short8*)(sp + 8);
        }
        __syncthreads();
#pragma unroll
        for (int j = 0; j < 8; ++j) T[dq + j][sr] = a0[j];
#pragma unroll
        for (int j = 0; j < 8; ++j) T[dq + 8 + j][sr] = a1[j];
        __syncthreads();
        const int scol = st * 64 + osq;
        if (scol + 8 <= VLD) {
            const short8 o0 = *(const short8*)&T[od][osq];
            const short8 o1 = *(const short8*)&T[od + 32][osq];
            *(short8*)(dst + (size_t)(bh * 64 + od) * VLD + scol) = o0;
            *(short8*)(dst + (size_t)(bh * 64 + od + 32) * VLD + scol) = o1;
        }
    }
}

// ---------------------------------------------------------------- MFMA flash attention (split bf16)
__global__ __launch_bounds__(256) void attn_mfma(const bf16* __restrict__ qkh,
                                                 const bf16* __restrict__ qkl,
                                                 const bf16* __restrict__ vth,
                                                 const bf16* __restrict__ vtl,
                                                 bf16* __restrict__ chi,
                                                 bf16* __restrict__ clo) {
    __shared__ short QPs[2][64][72];   // Q staging, then P
    __shared__ short Ks[2][64][72];
    __shared__ short Vs[2][64][72];    // Vt tile: [d][n]
    const int tid = threadIdx.x;
    const int qt = blockIdx.x, bh = blockIdx.y;
    const int b = bh >> 3, h = bh & 7;
    const int wave = tid >> 6, lane = tid & 63;
    const int lm = lane & 15, g = lane >> 4, q8 = g * 8;
    const int wq = wave * 16;
    const int r0 = tid >> 2, kq = (tid & 3) * 16;

    {
        const int q = qt * 64 + r0;
        short8 z = {0, 0, 0, 0, 0, 0, 0, 0};
        short8 a0 = z, a1 = z, b0 = z, b1 = z;
        if (q < SEQ) {
            const size_t base = (size_t)(b * SEQ + q) * 1536 + h * 64 + kq;
            a0 = *(const short8*)((const short*)qkh + base);
            a1 = *(const short8*)((const short*)qkh + base + 8);
            b0 = *(const short8*)((const short*)qkl + base);
            b1 = *(const short8*)((const short*)qkl + base + 8);
        }
        *(short8*)&QPs[0][r0][kq] = a0; *(short8*)&QPs[0][r0][kq + 8] = a1;
        *(short8*)&QPs[1][r0][kq] = b0; *(short8*)&QPs[1][r0][kq + 8] = b1;
    }
    __syncthreads();
    short8 qfh[2], qfl[2];
#pragma unroll
    for (int t = 0; t < 2; ++t) {
        qfh[t] = *(const short8*)&QPs[0][wq + lm][t * 32 + q8];
        qfl[t] = *(const short8*)&QPs[1][wq + lm][t * 32 + q8];
    }

    float m_i[4] = {-3e38f, -3e38f, -3e38f, -3e38f};
    float l_i[4] = {0.f, 0.f, 0.f, 0.f};
    f32x4 o[4];
#pragma unroll
    for (int dt = 0; dt < 4; ++dt) o[dt] = (f32x4){0.f, 0.f, 0.f, 0.f};

    for (int kb = 0; kb < SEQ; kb += 64) {
        __syncthreads();
        {
            const int kr = kb + r0;
            short8 z = {0, 0, 0, 0, 0, 0, 0, 0};
            short8 a0 = z, a1 = z, b0 = z, b1 = z;
            if (kr < SEQ) {
                const size_t base = (size_t)(b * SEQ + kr) * 1536 + 512 + h * 64 + kq;
                a0 = *(const short8*)((const short*)qkh + base);
                a1 = *(const short8*)((const short*)qkh + base + 8);
                b0 = *(const short8*)((const short*)qkl + base);
                b1 = *(const short8*)((const short*)qkl + base + 8);
            }
            *(short8*)&Ks[0][r0][kq] = a0; *(short8*)&Ks[0][r0][kq + 8] = a1;
            *(short8*)&Ks[1][r0][kq] = b0; *(short8*)&Ks[1][r0][kq + 8] = b1;
            const size_t vbase = (size_t)(bh * 64 + r0) * VLD + kb + kq;
            short8 v0 = z, v1 = z, w0 = z, w1 = z;
            if (kb + kq + 8 <= VLD) {
                v0 = *(const short8*)((const short*)vth + vbase);
                w0 = *(const short8*)((const short*)vtl + vbase);
            }
            if (kb + kq + 16 <= VLD) {
                v1 = *(const short8*)((const short*)vth + vbase + 8);
                w1 = *(const short8*)((const short*)vtl + vbase + 8);
            }
            *(short8*)&Vs[0][r0][kq] = v0; *(short8*)&Vs[0][r0][kq + 8] = v1;
            *(short8*)&Vs[1][r0][kq] = w0; *(short8*)&Vs[1][r0][kq + 8] = w1;
        }
        __syncthreads();
        f32x4 sac[4];
#pragma unroll
        for (int j = 0; j < 4; ++j) sac[j] = (f32x4){0.f, 0.f, 0.f, 0.f};
#pragma unroll
        for (int t = 0; t < 2; ++t) {
#pragma unroll
            for (int j = 0; j < 4; ++j) {
                const short8 kh = *(const short8*)&Ks[0][j * 16 + lm][t * 32 + q8];
                const short8 kl = *(const short8*)&Ks[1][j * 16 + lm][t * 32 + q8];
                sac[j] = __builtin_amdgcn_mfma_f32_16x16x32_bf16(qfh[t], kh, sac[j], 0, 0, 0);
                sac[j] = __builtin_amdgcn_mfma_f32_16x16x32_bf16(qfh[t], kl, sac[j], 0, 0, 0);
                sac[j] = __builtin_amdgcn_mfma_f32_16x16x32_bf16(qfl[t], kh, sac[j], 0, 0, 0);
            }
        }
        float alpha_v[4];
#pragma unroll
        for (int reg = 0; reg < 4; ++reg) {
            float sv[4];
            float rm = -3e38f;
#pragma unroll
            for (int j = 0; j < 4; ++j) {
                const int kc = kb + j * 16 + lm;
                float s = sac[j][reg] * 0.125f;
                s = (kc < SEQ) ? s : -3e38f;
                sv[j] = s;
                rm = fmaxf(rm, s);
            }
#pragma unroll
            for (int m = 1; m < 16; m <<= 1) rm = fmaxf(rm, __shfl_xor(rm, m));
            const float mn = fmaxf(m_i[reg], rm);
            const float al = expf(m_i[reg] - mn);
            float rs = 0.f;
            const int prow = wq + g * 4 + reg;
#pragma unroll
            for (int j = 0; j < 4; ++j) {
                const float pv = expf(sv[j] - mn);
                rs += pv;
                bf16 phb = __float2bfloat16(pv);
                bf16 plb = __float2bfloat16(pv - __bfloat162float(phb));
                QPs[0][prow][j * 16 + lm] = *reinterpret_cast<short*>(&phb);
                QPs[1][prow][j * 16 + lm] = *reinterpret_cast<short*>(&plb);
            }
#pragma unroll
            for (int m = 1; m < 16; m <<= 1) rs += __shfl_xor(rs, m);
            l_i[reg] = l_i[reg] * al + rs;
            m_i[reg] = mn;
            alpha_v[reg] = al;
        }
        const f32x4 av = {alpha_v[0], alpha_v[1], alpha_v[2], alpha_v[3]};
#pragma unroll
        for (int dt = 0; dt < 4; ++dt) o[dt] *= av;
        __syncthreads();
#pragma unroll
        for (int t = 0; t < 2; ++t) {
            const short8 ph = *(const short8*)&QPs[0][wq + lm][t * 32 + q8];
            const short8 pl = *(const short8*)&QPs[1][wq + lm][t * 32 + q8];
#pragma unroll
            for (int dt = 0; dt < 4; ++dt) {
                const short8 vh = *(const short8*)&Vs[0][dt * 16 + lm][t * 32 + q8];
                const short8 vl = *(const short8*)&Vs[1][dt * 16 + lm][t * 32 + q8];
                o[dt] = __builtin_amdgcn_mfma_f32_16x16x32_bf16(ph, vh, o[dt], 0, 0, 0);
                o[dt] = __builtin_amdgcn_mfma_f32_16x16x32_bf16(ph, vl, o[dt], 0, 0, 0);
                o[dt] = __builtin_amdgcn_mfma_f32_16x16x32_bf16(pl, vh, o[dt], 0, 0, 0);
            }
        }
    }
#pragma unroll
    for (int reg = 0; reg < 4; ++reg) {
        const int q = qt * 64 + wq + g * 4 + reg;
        if (q < SEQ) {
            const float inv = 1.0f / l_i[reg];
#pragma unroll
            for (int dt = 0; dt < 4; ++dt) {
                const size_t idx = (size_t)(b * SEQ + q) * E + h * 64 + dt * 16 + lm;
                split_store(o[dt][reg] * inv, chi, clo, idx);
            }
        }
    }
}

// ---------------------------------------------------------------- codebook row norms
__global__ __launch_bounds__(256) void cbnorm_kernel(const float* __restrict__ cb,
                                                     float* __restrict__ out) {
    const int lane = threadIdx.x & 63;
    const int row = blockIdx.x * 4 + (threadIdx.x >> 6);
    const float* p = cb + (size_t)row * E;
    const float4 v0 = *(const float4*)(p + lane * 4);
    const float4 v1 = *(const float4*)(p + 256 + lane * 4);
    float sq = v0.x * v0.x + v0.y * v0.y + v0.z * v0.z + v0.w * v0.w
             + v1.x * v1.x + v1.y * v1.y + v1.z * v1.z + v1.w * v1.w;
#pragma unroll
    for (int m = 1; m < 64; m <<= 1) sq += __shfl_xor(sq, m);
    if (lane == 0) out[row] = sq;
}

// ---------------------------------------------------------------- stage A: split-bf16 MFMA distance, per-row top2 partials
// grid (8 col-groups of 512, 125 row-blocks); 4 waves each own 32 rows x 128 cols.
// Per col-group running top-2 kept in regs; LDS-mediated merge (no shuffle trees).
// part[row*8 + colGroup] = (v1, idx1, v2, idx2)
__global__ __launch_bounds__(256) void argmin_mfma(
    const bf16* __restrict__ Ah, const bf16* __restrict__ Al,
    const bf16* __restrict__ Wh, const bf16* __restrict__ Wl,
    const float* __restrict__ cbn, float4* __restrict__ part) {
    __shared__ __align__(16) short sbuf[2][2][128][40];  // [A/W][plane][row][k+8pad]; aliased as mrg
    float4* mrg = reinterpret_cast<float4*>(&sbuf[0][0][0][0]);  // [row*17 + lm], 34816 B
    const int tid = threadIdx.x;
    const int rowBase = blockIdx.y * 128;
    const int wave = tid >> 6, lane = tid & 63;
    const int wm = wave * 32;         // wave's 32-row band
    const int lm = lane & 15;
    const int g = lane >> 4;
    const int q8 = g * 8;
    const int r0 = tid >> 2;          // 0..63
    const int kq = (tid & 3) * 8;     // 0,8,16,24
    const int own_row = tid >> 1;     // 0..127 (merge-phase ownership)
    const int own_half = tid & 1;

    float rv1 = 3e38f, rv2 = 3e38f;
    int rc1 = 0x7fffffff, rc2 = 0x7fffffff;

    for (int ct = 0; ct < 4; ++ct) {
        const int colBase = blockIdx.x * 512 + ct * 128;
        f32x4 acc[2][8];
#pragma unroll
        for (int i = 0; i < 2; ++i)
#pragma unroll
            for (int j = 0; j < 8; ++j)
                acc[i][j] = (f32x4){0.f, 0.f, 0.f, 0.f};

        for (int k0 = 0; k0 < E; k0 += 32) {
            __syncthreads();
            {
                const size_t a0 = (size_t)(rowBase + r0) * E + k0 + kq;
                const size_t a1 = (size_t)(rowBase + r0 + 64) * E + k0 + kq;
                const size_t w0 = (size_t)(colBase + r0) * E + k0 + kq;
                const size_t w1 = (size_t)(colBase + r0 + 64) * E + k0 + kq;
                *(short8*)&sbuf[0][0][r0][kq]      = *(const short8*)(Ah + a0);
                *(short8*)&sbuf[0][0][r0 + 64][kq] = *(const short8*)(Ah + a1);
                *(short8*)&sbuf[0][1][r0][kq]      = *(const short8*)(Al + a0);
                *(short8*)&sbuf[0][1][r0 + 64][kq] = *(const short8*)(Al + a1);
                *(short8*)&sbuf[1][0][r0][kq]      = *(const short8*)(Wh + w0);
                *(short8*)&sbuf[1][0][r0 + 64][kq] = *(const short8*)(Wh + w1);
                *(short8*)&sbuf[1][1][r0][kq]      = *(const short8*)(Wl + w0);
                *(short8*)&sbuf[1][1][r0 + 64][kq] = *(const short8*)(Wl + w1);
            }
            __syncthreads();
            short8 ah[2], al2[2], wh[8], wl[8];
#pragma unroll
            for (int i = 0; i < 2; ++i) {
                ah[i]  = *(const short8*)&sbuf[0][0][wm + i * 16 + lm][q8];
                al2[i] = *(const short8*)&sbuf[0][1][wm + i * 16 + lm][q8];
            }
#pragma unroll
            for (int j = 0; j < 8; ++j) {
                wh[j] = *(const short8*)&sbuf[1][0][j * 16 + lm][q8];
                wl[j] = *(const short8*)&sbuf[1][1][j * 16 + lm][q8];
            }
#pragma unroll
            for (int i = 0; i < 2; ++i)
#pragma unroll
                for (int j = 0; j < 8; ++j)
                    acc[i][j] = __builtin_amdgcn_mfma_f32_16x16x32_bf16(ah[i], wh[j], acc[i][j], 0, 0, 0);
#pragma unroll
            for (int i = 0; i < 2; ++i)
#pragma unroll
                for (int j = 0; j < 8; ++j)
                    acc[i][j] = __builtin_amdgcn_mfma_f32_16x16x32_bf16(ah[i], wl[j], acc[i][j], 0, 0, 0);
#pragma unroll
            for (int i = 0; i < 2; ++i)
#pragma unroll
                for (int j = 0; j < 8; ++j)
                    acc[i][j] = __builtin_amdgcn_mfma_f32_16x16x32_bf16(al2[i], wh[j], acc[i][j], 0, 0, 0);
        }

        // per-tile local top2 -> mrg LDS (aliases staging buffer)
        float nv[8];
#pragma unroll
        for (int j = 0; j < 8; ++j) nv[j] = cbn[colBase + j * 16 + lm];
        __syncthreads();   // all frag reads done before overwrite
#pragma unroll
        for (int i = 0; i < 2; ++i) {
#pragma unroll
            for (int reg = 0; reg < 4; ++reg) {
                const int row_local = wm + i * 16 + g * 4 + reg;
                float v1 = 3e38f, v2 = 3e38f;
                int c1 = 0x7fffffff, c2 = 0x7fffffff;
#pragma unroll
                for (int j = 0; j < 8; ++j) {
                    const float d = nv[j] - 2.0f * acc[i][j][reg];
                    t2_ins(d, colBase + j * 16 + lm, v1, c1, v2, c2);
                }
                mrg[row_local * 17 + lm] = make_float4(v1, (float)c1, v2, (float)c2);
            }
        }
        __syncthreads();
        // merge: thread owns row own_row, half own_half (8 entries each)
        {
            float mv1 = 3e38f, mv2 = 3e38f;
            int mc1 = 0x7fffffff, mc2 = 0x7fffffff;
#pragma unroll
            for (int e = 0; e < 8; ++e) {
                const float4 p = mrg[own_row * 17 + own_half * 8 + e];
                t2_ins(p.x, (int)p.y, mv1, mc1, mv2, mc2);
                t2_ins(p.z, (int)p.w, mv1, mc1, mv2, mc2);
            }
            const float pv1 = __shfl_xor(mv1, 1); const int pc1 = __shfl_xor(mc1, 1);
            const float pv2 = __shfl_xor(mv2, 1); const int pc2 = __shfl_xor(mc2, 1);
            t2_ins(pv1, pc1, mv1, mc1, mv2, mc2);
            t2_ins(pv2, pc2, mv1, mc1, mv2, mc2);
            t2_ins(mv1, mc1, rv1, rc1, rv2, rc2);
            t2_ins(mv2, mc2, rv1, rc1, rv2, rc2);
        }
    }
    if (own_half == 0)
        part[(size_t)(rowBase + own_row) * 8 + blockIdx.x] =
            make_float4(rv1, (float)rc1, rv2, (float)rc2);
}

// ---------------------------------------------------------------- stage B: merge 8 partials, exact fp32 rescore of top2
__global__ __launch_bounds__(256) void argmin_exact(const float4* __restrict__ part,
                                                    const float* __restrict__ fc,
                                                    const float* __restrict__ cb,
                                                    const float* __restrict__ cbn,
                                                    float* __restrict__ tokf) {
    const int wave = threadIdx.x >> 6, lane = threadIdx.x & 63;
    const int r = blockIdx.x * 4 + wave;   // 4000 blocks
    float v1 = 3e38f, v2 = 3e38f;
    int c1 = 0x7fffffff, c2 = 0x7fffffff;
    if (lane < 8) {
        const float4 p = part[(size_t)r * 8 + lane];
        v1 = p.x; c1 = (int)p.y; v2 = p.z; c2 = (int)p.w;
    }
#pragma unroll
    for (int m = 1; m < 8; m <<= 1) {
        const float w1 = __shfl_xor(v1, m); const int d1i = __shfl_xor(c1, m);
        const float w2 = __shfl_xor(v2, m); const int d2i = __shfl_xor(c2, m);
        t2_ins(w1, d1i, v1, c1, v2, c2);
        t2_ins(w2, d2i, v1, c1, v2, c2);
    }
    c1 = __shfl(c1, 0);
    c2 = __shfl(c2, 0);
    // exact fp32 d2 for c1, c2
    const float* fr = fc + (size_t)r * E + lane * 8;
    const float* p1 = cb + (size_t)c1 * E + lane * 8;
    const float* p2 = cb + (size_t)c2 * E + lane * 8;
    float d1 = 0.f, d2 = 0.f;
#pragma unroll
    for (int j = 0; j < 8; ++j) {
        const float f = fr[j];
        d1 += f * p1[j];
        d2 += f * p2[j];
    }
#pragma unroll
    for (int m = 1; m < 64; m <<= 1) {
        d1 += __shfl_xor(d1, m);
        d2 += __shfl_xor(d2, m);
    }
    d1 = cbn[c1] - 2.0f * d1;
    d2 = cbn[c2] - 2.0f * d2;
    const int win = ((d1 < d2) || (d1 == d2 && c1 < c2)) ? c1 : c2;
    if (lane == 0) tokf[r] = (float)win;
}

// ---------------------------------------------------------------- launch
extern "C" void kernel_launch(void* const* d_in, const int* in_sizes, int n_in,
                              void* d_out, int out_size, void* d_ws, size_t ws_size,
                              hipStream_t stream) {
    const int* noisy = (const int*)d_in[0];
    const float* codebook = (const float*)d_in[1];
    const float* pos_enc = (const float*)d_in[2];
    const float* qkv_w = (const float*)d_in[3];
    const float* qkv_b = (const float*)d_in[4];
    const float* out_w = (const float*)d_in[5];
    const float* out_b = (const float*)d_in[6];
    const float* ln1_g = (const float*)d_in[7];
    const float* ln1_b = (const float*)d_in[8];
    const float* ln2_g = (const float*)d_in[9];
    const float* ln2_b = (const float*)d_in[10];
    const float* ff1_w = (const float*)d_in[11];
    const float* ff1_b = (const float*)d_in[12];
    const float* ff2_w = (const float*)d_in[13];
    const float* ff2_b = (const float*)d_in[14];
    const float* fin_g = (const float*)d_in[15];
    const float* fin_b = (const float*)d_in[16];
    const float* pp1_w = (const float*)d_in[17];
    const float* pp1_b = (const float*)d_in[18];
    const float* pp_ln_g = (const float*)d_in[19];
    const float* pp_ln_b = (const float*)d_in[20];
    const float* pp2_w = (const float*)d_in[21];
    const float* pp2_b = (const float*)d_in[22];
    const float* res_w = (const float*)d_in[23];
    const float* fc1_w = (const float*)d_in[24];
    const float* fc1_b = (const float*)d_in[25];
    const float* fc_ln_g = (const float*)d_in[26];
    const float* fc_ln_b = (const float*)d_in[27];
    const float* fc2_w = (const float*)d_in[28];
    const float* fc2_b = (const float*)d_in[29];

    // workspace (floats), total 41,025,536 floats = 164.1 MB
    float* ws = (float*)d_ws;
    float* y = ws;                        // [0, 8.192M)
    float* REG = ws + 8192000;            // [8.192M, 32.768M)
    bf16* qkvh = (bf16*)REG;              // 16000x1536 shorts
    bf16* qkvl = qkvh + 24576000;
    bf16* mid_hi = (bf16*)REG;            // FF phase: 16000x1024
    bf16* mid_lo = mid_hi + 16384000;
    float* slotA = REG;                   // tail: e planes / fc fp32
    float* slotB = REG + 8192000;         // tail: pp1/fc1 fp32 tmp, then cbn+partials
    bf16* e_hi = (bf16*)slotA;
    bf16* e_lo = e_hi + 8192000;
    float* WV = ws + 32768000;            // [32.768M, 41.0255M): Vt planes OR weight splits OR cb planes
    bf16* vth = (bf16*)WV;                // 8192 x VLD
    bf16* vtl = vth + 8192 * VLD;
    bf16* wA_hi = (bf16*)WV;              // cap 2048x512 each
    bf16* wA_lo = wA_hi + 1048576;
    bf16* wB_hi = wA_lo + 1048576;
    bf16* wB_lo = wB_hi + 1048576;
    bf16* cbh = wB_lo + 1048576;          // 4096x512, after weights (tail only)
    bf16* cbl = cbh + 2097152;
    float* cbn = slotB;                   // tail-only
    float4* part = (float4*)(slotB + 4096);  // 16000 x 8 float4 = 512k floats
    // h planes live in d_out (dead before final outputs are written)
    bf16* h_hi = (bf16*)d_out;
    bf16* h_lo = h_hi + 8192000;
    bf16* fcp_hi = (bf16*)d_out;          // fc planes overwrite h planes at the very end
    bf16* fcp_lo = fcp_hi + 8192000;
    float* tokf = (float*)d_out + 8192000;

    const dim3 blk(256);
    const dim3 g512(4, 125), g1024(8, 125), g1536(12, 125);

    embed_kernel<<<dim3(NTOK), dim3(128), 0, stream>>>(noisy, codebook, pos_enc, y);

    for (int l = 0; l < 4; ++l) {
        ln_planes<0><<<dim3(4000), blk, 0, stream>>>(y, h_hi, h_lo, ln1_g + l * E, ln1_b + l * E);
        split_w<<<dim3(3072), blk, 0, stream>>>(qkv_w + (size_t)l * 1536 * E, E, 9, 1536 * E, wA_hi, wA_lo);
        gemm_split<4><<<g1536, blk, 0, stream>>>(
            h_hi, h_lo, E, wA_hi, wA_lo, E, qkv_b + (size_t)l * 1536,
            nullptr, 0, qkvh, qkvl, 1536, nullptr, nullptr, nullptr, nullptr, E);
        vtrans<<<dim3(16, 128), blk, 0, stream>>>(qkvh, qkvl, vth, vtl);  // overwrites wA (dead)
        attn_mfma<<<dim3(16, 128), blk, 0, stream>>>(qkvh, qkvl, vth, vtl, h_hi, h_lo);
        split_w<<<dim3(1024), blk, 0, stream>>>(out_w + (size_t)l * E * E, E, 9, E * E, wB_hi, wB_lo);
        gemm_split<1><<<g512, blk, 0, stream>>>(
            h_hi, h_lo, E, wB_hi, wB_lo, E, out_b + (size_t)l * E,
            y, E, nullptr, nullptr, 0, nullptr, nullptr, nullptr, nullptr, E);
        ln_planes<0><<<dim3(4000), blk, 0, stream>>>(y, h_hi, h_lo, ln2_g + l * E, ln2_b + l * E);
        split_w<<<dim3(4096), blk, 0, stream>>>(ff1_w + (size_t)l * FFD * E, E, 9, FFD * E, wA_hi, wA_lo);
        split_w<<<dim3(4096), blk, 0, stream>>>(ff2_w + (size_t)l * E * FFD, FFD, 11, E * FFD, wB_hi, wB_lo);
        for (int c = 0; c < 2; ++c) {
            gemm_split<2><<<g1024, blk, 0, stream>>>(
                h_hi, h_lo, E, wA_hi + (size_t)c * 1024 * E, wA_lo + (size_t)c * 1024 * E, E,
                ff1_b + (size_t)l * FFD + c * 1024,
                nullptr, 0, mid_hi, mid_lo, 1024, nullptr, nullptr, nullptr, nullptr, E);
            gemm_split<1><<<g512, blk, 0, stream>>>(
                mid_hi, mid_lo, 1024, wB_hi + c * 1024, wB_lo + c * 1024, FFD,
                (c == 0) ? (ff2_b + (size_t)l * E) : nullptr,
                y, E, nullptr, nullptr, 0, nullptr, nullptr, nullptr, nullptr, 1024);
        }
    }

    // tail
    ln_planes<0><<<dim3(4000), blk, 0, stream>>>(y, h_hi, h_lo, fin_g, fin_b);
    split_w<<<dim3(1024), blk, 0, stream>>>(pp1_w, E, 9, E * E, wA_hi, wA_lo);
    gemm_split<0><<<g512, blk, 0, stream>>>(
        h_hi, h_lo, E, wA_hi, wA_lo, E, pp1_b,
        slotB, E, nullptr, nullptr, 0, nullptr, nullptr, nullptr, nullptr, E);
    ln_planes<1><<<dim3(4000), blk, 0, stream>>>(slotB, h_hi, h_lo, pp_ln_g, pp_ln_b);
    split_w<<<dim3(1024), blk, 0, stream>>>(pp2_w, E, 9, E * E, wB_hi, wB_lo);
    gemm_split<3><<<g512, blk, 0, stream>>>(
        h_hi, h_lo, E, wB_hi, wB_lo, E, pp2_b,
        nullptr, 0, e_hi, e_lo, E, noisy, codebook, pos_enc, res_w, E);
    split_w<<<dim3(1024), blk, 0, stream>>>(fc1_w, E, 9, E * E, wA_hi, wA_lo);
    gemm_split<0><<<g512, blk, 0, stream>>>(
        e_hi, e_lo, E, wA_hi, wA_lo, E, fc1_b,
        slotB, E, nullptr, nullptr, 0, nullptr, nullptr, nullptr, nullptr, E);
    ln_planes<1><<<dim3(4000), blk, 0, stream>>>(slotB, h_hi, h_lo, fc_ln_g, fc_ln_b);
    split_w<<<dim3(1024), blk, 0, stream>>>(fc2_w, E, 9, E * E, wB_hi, wB_lo);
    gemm_split<0><<<g512, blk, 0, stream>>>(
        h_hi, h_lo, E, wB_hi, wB_lo, E, fc2_b,
        slotA, E, nullptr, nullptr, 0, nullptr, nullptr, nullptr, nullptr, E);   // fc fp32 -> slotA

    // argmin: approx MFMA top2 (running over 4 col-tiles/block) + exact fp32 rescore
    split_w<<<dim3(32000), blk, 0, stream>>>(slotA, E, 9, NTOK * E, fcp_hi, fcp_lo);  // fc planes (h dead)
    split_w<<<dim3(8192), blk, 0, stream>>>(codebook, E, 9, CBN * E, cbh, cbl);
    cbnorm_kernel<<<dim3(1024), blk, 0, stream>>>(codebook, cbn);
    argmin_mfma<<<dim3(8, 125), blk, 0, stream>>>(fcp_hi, fcp_lo, cbh, cbl, cbn, part);
    argmin_exact<<<dim3(4000), blk, 0, stream>>>(part, slotA, codebook, cbn, tokf);
    hipMemcpyAsync(d_out, slotA, (size_t)8192000 * 4, hipMemcpyDeviceToDevice, stream);
}